// Round 13
// baseline (6328.625 us; speedup 1.0000x reference)
//
#include <hip/hip_runtime.h>
#include <stdint.h>

#define B_ 16
#define S_ 512
#define D_ 1024
#define H4 512
#define G_ 256

typedef unsigned short u16;
using short8 = __attribute__((ext_vector_type(8))) short;
using f32x4  = __attribute__((ext_vector_type(4))) float;

__device__ __forceinline__ u16 f2bf(float f){
  unsigned int u = __float_as_uint(f);
  u += 0x7fffu + ((u >> 16) & 1u);
  return (u16)(u >> 16);
}
__device__ __forceinline__ float bf2f(u16 h){
  return __uint_as_float(((unsigned int)h) << 16);
}

// ---------------- single-dispatch f32 -> bf16 convert over all segments ----------------
struct CvtSegs {
  const float4* src[14];
  short4* dst[14];
  int blk0[15];
};
__global__ __launch_bounds__(256) void cvt_multi(CvtSegs cs){
  int blk = blockIdx.x;
  int s = 0;
  #pragma unroll
  for (int k = 0; k < 14; ++k) if (cs.blk0[k + 1] <= blk) s = k + 1;
  int i = (blk - cs.blk0[s]) * 256 + threadIdx.x;
  float4 v = cs.src[s][i];
  short4 o;
  o.x = (short)f2bf(v.x); o.y = (short)f2bf(v.y);
  o.z = (short)f2bf(v.z); o.w = (short)f2bf(v.w);
  cs.dst[s][i] = o;
}

// ---------------- LSTM bias sums (bih+bhh) ----------------
__global__ __launch_bounds__(256) void bias_prep(const float* a,const float* b,const float* c,const float* d,
                                                 const float* e,const float* f,const float* g,const float* h,
                                                 float* out){
  int i = blockIdx.x * 256 + threadIdx.x;
  if (i >= 2048) return;
  int p = i >> 9, k = i & 511;
  const float* x1 = (p==0)?a:(p==1)?c:(p==2)?e:g;
  const float* x2 = (p==0)?b:(p==1)?d:(p==2)?f:h;
  out[i] = x1[k] + x2[k];
}

// ---------------- MFMA BT-GEMM body (256-lane slice, 64x64 tile) ----------------
// EPI: 0=none, 1=relu, 2=score-mask (sigmoid+adj+eye, ex=adj), 3=row-scale (ex=rinv)
// PERM: 0 = row-major out, 2 = gate-interleaved X layout
template<int EPI, bool OUT_BF16, int PERM, bool RESID>
__device__ __forceinline__ void gemm_bt_body(
    const u16* __restrict__ A, const u16* __restrict__ W,
    const float* __restrict__ bias, const u16* __restrict__ resid,
    const float* __restrict__ ex,
    void* __restrict__ outp, int M, int N, int K,
    long sA, long sW, long sO, int bx, int by, int bz, int tid)
{
  const u16* Ab = A + (long)bz * sA;
  const u16* Wb = W + (long)bz * sW;
  const int bm0 = by * 64, bn0 = bx * 64;
  const int l = tid & 63, wid = tid >> 6;
  const int wm = (wid >> 1) * 32, wn = (wid & 1) * 32;
  const int lr = l & 15, lk8 = (l >> 4) * 8;

  const f32x4 z4 = {0.f, 0.f, 0.f, 0.f};
  f32x4 acc[2][2] = {{z4, z4}, {z4, z4}};

  const u16* Ap0 = Ab + (long)(bm0 + wm + lr) * K + lk8;
  const u16* Wp0 = Wb + (long)(bn0 + wn + lr) * K + lk8;
  for (int k0 = 0; k0 < K; k0 += 32) {
    short8 a0 = *reinterpret_cast<const short8*>(Ap0 + k0);
    short8 a1 = *reinterpret_cast<const short8*>(Ap0 + (long)16 * K + k0);
    short8 b0 = *reinterpret_cast<const short8*>(Wp0 + k0);
    short8 b1 = *reinterpret_cast<const short8*>(Wp0 + (long)16 * K + k0);
    acc[0][0] = __builtin_amdgcn_mfma_f32_16x16x32_bf16(a0, b0, acc[0][0], 0, 0, 0);
    acc[0][1] = __builtin_amdgcn_mfma_f32_16x16x32_bf16(a0, b1, acc[0][1], 0, 0, 0);
    acc[1][0] = __builtin_amdgcn_mfma_f32_16x16x32_bf16(a1, b0, acc[1][0], 0, 0, 0);
    acc[1][1] = __builtin_amdgcn_mfma_f32_16x16x32_bf16(a1, b1, acc[1][1], 0, 0, 0);
  }
  #pragma unroll
  for (int mt = 0; mt < 2; ++mt)
  #pragma unroll
  for (int nt = 0; nt < 2; ++nt) {
    int n = bn0 + wn + 16 * nt + lr;
    float bv = bias ? bias[n] : 0.f;
    #pragma unroll
    for (int r = 0; r < 4; ++r) {
      int m = bm0 + wm + 16 * mt + (l >> 4) * 4 + r;
      float v = acc[mt][nt][r] + bv;
      if (EPI == 1) v = fmaxf(v, 0.f);
      if (EPI == 2) {
        float sg = __fdividef(1.f, 1.f + __expf(-v));
        v = (n == m) ? (sg + 1e-5f) : sg * ex[((long)bz * 512 + m) * 512 + n];
      }
      if (EPI == 3) v *= ex[(long)bz * 512 + m];
      if (RESID) v += bf2f(resid[(long)m * N + n]);
      long oi;
      if (PERM == 2) {
        int t = m & 511, b = m >> 9;
        oi = (long)((t * 16 + b) * 128 + (n & 127)) * 4 + (n >> 7);
      } else {
        oi = (long)bz * sO + (long)m * N + n;
      }
      if (OUT_BF16) ((u16*)outp)[oi] = f2bf(v);
      else          ((float*)outp)[oi] = v;
    }
  }
}

// ---------------- fused f/b input projections (PERM2, f32 out) ----------------
__global__ __launch_bounds__(256) void proj2(
    const u16* __restrict__ A, const u16* __restrict__ W0, const u16* __restrict__ W1,
    const float* __restrict__ bias, float* __restrict__ O0, float* __restrict__ O1, int K)
{
  int z = blockIdx.z;
  gemm_bt_body<0, false, 2, false>(A, z ? W1 : W0, bias + z * 512, nullptr, nullptr,
                                   z ? O1 : O0, 8192, 512, K, 0, 0, 0,
                                   blockIdx.x, blockIdx.y, 0, threadIdx.x);
}

// ---------------- transpose body (256-lane slice, valid-predicated, fixed barriers) ----------
__device__ __forceinline__ void transpose_body(const u16* __restrict__ in, u16* __restrict__ out,
                                               int bz, int s0, int d0, int tid,
                                               u16 (*tile)[33], bool valid)
{
  int tx = tid & 31, ty = (tid >> 5) & 7;
  const u16* ip = in + (long)bz * 512 * 256;
  u16* op = out + (long)bz * 256 * 512;
  if (valid) {
    #pragma unroll
    for (int k = 0; k < 32; k += 8) tile[ty + k][tx] = ip[(long)(s0 + ty + k) * 256 + d0 + tx];
  }
  __syncthreads();
  if (valid) {
    #pragma unroll
    for (int k = 0; k < 32; k += 8) op[(long)(d0 + ty + k) * 512 + s0 + tx] = tile[tx][ty + k];
  }
  __syncthreads();
}

// ---------------- row-sum reciprocal body (256-lane slice) ----------------
__device__ __forceinline__ void rowsum_body(const u16* __restrict__ abf, float* __restrict__ rinv,
                                            int bx, int bz, int tid)
{
  int row = bx * 4 + ((tid >> 6) & 3);
  int l = tid & 63;
  short8 v = *reinterpret_cast<const short8*>(abf + ((size_t)bz * 512 + row) * 512 + l * 8);
  float s = 0.f;
  #pragma unroll
  for (int k = 0; k < 8; ++k) s += bf2f((u16)v[k]);
  #pragma unroll
  for (int off = 32; off; off >>= 1) s += __shfl_xor(s, off);
  if (l == 0) rinv[bz * 512 + row] = __fdividef(1.f, s);
}

// ---------------- LSTM scan v9: 8 blocks (dir x 4-batch group), dense gates ----------------
__device__ __forceinline__ void lstm_scan9_body(
    const float* __restrict__ X, const u16* __restrict__ Whh,
    u16* __restrict__ Hout, int dir, int bat0)
{
  __shared__ __align__(16) u16 hbuf[2][16][136];

  const int tid = threadIdx.x;
  const int l = tid & 63, w = tid >> 6;
  const int lr = l & 15, lk = l >> 4;

  short8 bfrag[4][4];
  #pragma unroll
  for (int g = 0; g < 4; ++g)
    #pragma unroll
    for (int ks = 0; ks < 4; ++ks)
      bfrag[g][ks] = *reinterpret_cast<const short8*>(
          Whh + (g * 128 + 16 * w + lr) * 128 + 32 * ks + 8 * lk);

  for (int i = tid; i < 2 * 16 * 136; i += 512) ((u16*)hbuf)[i] = 0;

  float c = 0.f;
  const f32x4 z4 = {0.f, 0.f, 0.f, 0.f};

  auto ldX = [&](int t) -> float4 {
    int ta = dir ? (S_ - 1 - t) : t;
    return *reinterpret_cast<const float4*>(
        X + (size_t)((ta * 16 + bat0 + lk) * 128 + 16 * w + lr) * 4);
  };
  float4 xA = ldX(0), xB = ldX(1), xC = ldX(2), xD;
  __syncthreads();

  auto step = [&](int t, float4& xc, float4& xt, int tload) {
    const int p = t & 1;
    short8 af[4];
    #pragma unroll
    for (int ks = 0; ks < 4; ++ks)
      af[ks] = *reinterpret_cast<const short8*>(&hbuf[p][lr][32 * ks + 8 * lk]);
    f32x4 acc[4] = {z4, z4, z4, z4};
    #pragma unroll
    for (int g = 0; g < 4; ++g)
      #pragma unroll
      for (int ks = 0; ks < 4; ++ks)
        acc[g] = __builtin_amdgcn_mfma_f32_16x16x32_bf16(af[ks], bfrag[g][ks], acc[g], 0, 0, 0);
    if (tload < S_) xt = ldX(tload);
    float zi = acc[0][0] + xc.x;
    float zf = acc[1][0] + xc.y;
    float zg = acc[2][0] + xc.z;
    float zo = acc[3][0] + xc.w;
    float si = __fdividef(1.f, 1.f + __expf(-zi));
    float sf = __fdividef(1.f, 1.f + __expf(-zf));
    float so = __fdividef(1.f, 1.f + __expf(-zo));
    float eg = __expf(2.f * zg);
    float tg = 1.f - __fdividef(2.f, eg + 1.f);
    c = sf * c + si * tg;
    float ec = __expf(2.f * c);
    float tc = 1.f - __fdividef(2.f, ec + 1.f);
    u16 hb = f2bf(so * tc);
    int ta = dir ? (S_ - 1 - t) : t;
    hbuf[p ^ 1][4 * lk][16 * w + lr] = hb;
    Hout[((size_t)(bat0 + lk) * S_ + ta) * 256 + dir * 128 + 16 * w + lr] = hb;
    asm volatile("s_waitcnt lgkmcnt(0)" ::: "memory");
    __builtin_amdgcn_s_barrier();
  };

  for (int t = 0; t < S_; t += 4) {
    step(t,     xA, xD, t + 3);
    step(t + 1, xB, xA, t + 4);
    step(t + 2, xC, xB, t + 5);
    step(t + 3, xD, xC, t + 6);
  }
}

// ---------------- persistent GAT workers with device-scope flag barriers ----------------
struct GatArgs {
  const u16 *xbf, *wfc1;
  const float *fc1b;
  const u16 *wattn; const float *wattnb;
  const u16 *wlin0; const float *lin0b;
  const u16 *wlin1; const float *lin1b;
  const u16 *wlinf; const float *linfb;
  const float *adj;
  u16 *gA, *gB, *qb, *gT, *t1, *t2, *abf;
  float *rinv;
  unsigned *flags;
};

// W = number of worker BLOCKS (496); V = 2W virtual 256-thread workers.
__device__ __forceinline__ void gat_part(const GatArgs& a, int wid, int W, int part,
                                         u16 (*myTile)[33])
{
  const int half = threadIdx.x >> 8;
  const int V = 2 * W;
  const int vw = wid * 2 + half;
  const int tid = threadIdx.x & 255;
  unsigned* F = a.flags + part * 16;
  int s = 0;

  auto sync_stage = [&]() {
    __syncthreads();
    __threadfence();
    if (threadIdx.x == 0) {
      __hip_atomic_fetch_add(F + s, 1u, __ATOMIC_RELEASE, __HIP_MEMORY_SCOPE_AGENT);
      while (__hip_atomic_load(F + s, __ATOMIC_ACQUIRE, __HIP_MEMORY_SCOPE_AGENT) < (unsigned)W)
        __builtin_amdgcn_s_sleep(32);
    }
    __syncthreads();
    __threadfence();
    ++s;
  };

  if (part == 0) {
    if (vw < 512)
      gemm_bt_body<0, true, 0, false>(a.xbf, a.wfc1, a.fc1b, nullptr, nullptr, a.gA,
                                      8192, 256, 1024, 0, 0, 0, vw & 3, vw >> 2, 0, tid);
    sync_stage();
  }

  for (int l = part * 2; l < part * 2 + 2; ++l) {
    const u16* in = (l & 1) ? a.gB : a.gA;
    u16* out      = (l & 1) ? a.gA : a.gB;
    // stage: wattn (512 tiles) + transpose (2048 tiles, fixed 3 iters, predicated)
    if (vw < 512)
      gemm_bt_body<0, true, 0, false>(in, a.wattn + l * 65536, a.wattnb + l * 256,
                                      nullptr, nullptr, a.qb,
                                      8192, 256, 256, 0, 0, 0, vw & 3, vw >> 2, 0, tid);
    #pragma unroll
    for (int i = 0; i < 3; ++i) {
      int t = vw + i * V;
      bool valid = t < 2048;
      int bz = valid ? (t >> 7) : 0, rem = valid ? (t & 127) : 0;
      transpose_body(in, a.gT, bz, (rem & 15) * 32, (rem >> 4) * 32, tid, myTile, valid);
    }
    sync_stage();
    // stage: score + mask (1024 tiles)
    for (int t = vw; t < 1024; t += V)
      gemm_bt_body<2, true, 0, false>(a.qb, in, nullptr, nullptr, a.adj, a.abf,
                                      512, 512, 256, 131072, 131072, 262144,
                                      t & 7, (t >> 3) & 7, t >> 6, tid);
    sync_stage();
    // stage: rowsum (2048 units)
    for (int t = vw; t < 2048; t += V)
      rowsum_body(a.abf, a.rinv, t & 127, t >> 7, tid);
    sync_stage();
    // stage: AV * rinv (512 tiles)
    if (vw < 512)
      gemm_bt_body<3, true, 0, false>(a.abf, a.gT, nullptr, nullptr, a.rinv, a.t1,
                                      512, 256, 512, 262144, 131072, 131072,
                                      vw & 3, (vw >> 2) & 7, vw >> 5, tid);
    sync_stage();
    // stage: lin0+relu (512 tiles)
    if (vw < 512)
      gemm_bt_body<1, true, 0, false>(a.t1, a.wlin0 + l * 65536, a.lin0b + l * 256,
                                      nullptr, nullptr, a.t2,
                                      8192, 256, 256, 0, 0, 0, vw & 3, vw >> 2, 0, tid);
    sync_stage();
    // stage: lin1+relu+resid (512 tiles)
    if (vw < 512)
      gemm_bt_body<1, true, 0, true>(a.t2, a.wlin1 + l * 65536, a.lin1b + l * 256,
                                     in, nullptr, out,
                                     8192, 256, 256, 0, 0, 0, vw & 3, vw >> 2, 0, tid);
    sync_stage();
  }

  if (part == 1) {
    if (vw < 512)
      gemm_bt_body<0, true, 0, false>(a.gA, a.wlinf, a.linfb, nullptr, nullptr, a.t2,
                                      8192, 256, 256, 0, 0, 0, vw & 3, vw >> 2, 0, tid);
  }
}

// ---------------- fused dispatch: blocks 0..7 = scan, blocks 8..503 = GAT workers ----------------
__global__ __launch_bounds__(512, 4) void scan_gat(
    const float* __restrict__ Xf, const float* __restrict__ Xb,
    const u16* __restrict__ Whhf, const u16* __restrict__ Whhb,
    u16* __restrict__ Hout, GatArgs ga, int part, int W)
{
  if (blockIdx.x < 8) {
    int dir = blockIdx.x & 1, bat0 = (blockIdx.x >> 1) * 4;
    lstm_scan9_body(dir ? Xb : Xf, dir ? Whhb : Whhf, Hout, dir, bat0);
  } else {
    __shared__ __align__(16) u16 tiles[2][32][33];
    gat_part(ga, blockIdx.x - 8, W, part, tiles[threadIdx.x >> 8]);
  }
}

// ---------------- coalesced mean over S of concat[lstm_out, g_final] ----------------
__global__ __launch_bounds__(256) void mean_cat(
    const u16* __restrict__ lstm, const u16* __restrict__ gf, float* __restrict__ dout)
{
  int b = blockIdx.x, tid = threadIdx.x;
  float sl = 0.f, sg = 0.f;
  for (int t = 0; t < 512; ++t) {
    sl += bf2f(lstm[((size_t)b * 512 + t) * 256 + tid]);
    sg += bf2f(gf[((size_t)b * 512 + t) * 256 + tid]);
  }
  dout[32 + b * 512 + tid]       = sl * (1.f / 512.f);
  dout[32 + b * 512 + 256 + tid] = sg * (1.f / 512.f);
}

// ---------------- head: fcA -> leaky -> fcB -> leaky -> fcC ----------------
__global__ __launch_bounds__(256) void head_kernel(
    const float* __restrict__ hidden,
    const float* __restrict__ fcA_W, const float* __restrict__ fcA_b,
    const float* __restrict__ fcB_W, const float* __restrict__ fcB_b,
    const float* __restrict__ fcC_W, const float* __restrict__ fcC_b,
    float* __restrict__ y)
{
  __shared__ float hb[16 * 512];
  __shared__ float ab[16 * 128];
  __shared__ float bb[16 * 32];
  int tid = threadIdx.x;
  for (int i = tid; i < 8192; i += 256) hb[i] = hidden[i];
  __syncthreads();
  for (int o = tid; o < 2048; o += 256) {
    int b = o >> 7, jj = o & 127;
    float acc = fcA_b[jj];
    const float* wrow = fcA_W + jj * 512;
    const float* hrow = hb + b * 512;
    for (int k = 0; k < 512; ++k) acc += hrow[k] * wrow[k];
    ab[o] = acc > 0.f ? acc : 0.1f * acc;
  }
  __syncthreads();
  for (int o = tid; o < 512; o += 256) {
    int b = o >> 5, jj = o & 31;
    float acc = fcB_b[jj];
    for (int k = 0; k < 128; ++k) acc += ab[b * 128 + k] * fcB_W[jj * 128 + k];
    bb[o] = acc > 0.f ? acc : 0.1f * acc;
  }
  __syncthreads();
  if (tid < 32) {
    int b = tid >> 1, jj = tid & 1;
    float acc = fcC_b[jj];
    for (int k = 0; k < 32; ++k) acc += bb[b * 32 + k] * fcC_W[jj * 32 + k];
    y[b * 2 + jj] = acc;
  }
}

extern "C" void kernel_launch(void* const* d_in, const int* in_sizes, int n_in,
                              void* d_out, int out_size, void* d_ws, size_t ws_size,
                              hipStream_t stream)
{
  const float* x       = (const float*)d_in[0];
  const float* adj     = (const float*)d_in[1];
  const float* l0f_Wih = (const float*)d_in[2];
  const float* l0f_Whh = (const float*)d_in[3];
  const float* l0f_bih = (const float*)d_in[4];
  const float* l0f_bhh = (const float*)d_in[5];
  const float* l0b_Wih = (const float*)d_in[6];
  const float* l0b_Whh = (const float*)d_in[7];
  const float* l0b_bih = (const float*)d_in[8];
  const float* l0b_bhh = (const float*)d_in[9];
  const float* l1f_Wih = (const float*)d_in[10];
  const float* l1f_Whh = (const float*)d_in[11];
  const float* l1f_bih = (const float*)d_in[12];
  const float* l1f_bhh = (const float*)d_in[13];
  const float* l1b_Wih = (const float*)d_in[14];
  const float* l1b_Whh = (const float*)d_in[15];
  const float* l1b_bih = (const float*)d_in[16];
  const float* l1b_bhh = (const float*)d_in[17];
  const float* fc1_W   = (const float*)d_in[18];
  const float* fc1_b   = (const float*)d_in[19];
  const float* wattn_W = (const float*)d_in[20];
  const float* wattn_b = (const float*)d_in[21];
  const float* lin0_W  = (const float*)d_in[22];
  const float* lin0_b  = (const float*)d_in[23];
  const float* lin1_W  = (const float*)d_in[24];
  const float* lin1_b  = (const float*)d_in[25];
  const float* linf_W  = (const float*)d_in[26];
  const float* linf_b  = (const float*)d_in[27];
  const float* fcA_W   = (const float*)d_in[28];
  const float* fcA_b   = (const float*)d_in[29];
  const float* fcB_W   = (const float*)d_in[30];
  const float* fcB_b   = (const float*)d_in[31];
  const float* fcC_W   = (const float*)d_in[32];
  const float* fcC_b   = (const float*)d_in[33];

  char* wp = (char*)d_ws;
  auto alloc = [&](size_t n) -> void* { void* p = wp; wp += (n + 255) & ~(size_t)255; return p; };

  unsigned* flags = (unsigned*)alloc(256);
  u16* x_bf     = (u16*)alloc((size_t)B_ * S_ * D_ * 2);
  u16* w0f_ih   = (u16*)alloc((size_t)512 * 1024 * 2);
  u16* w0b_ih   = (u16*)alloc((size_t)512 * 1024 * 2);
  u16* w1f_ih   = (u16*)alloc((size_t)512 * 256 * 2);
  u16* w1b_ih   = (u16*)alloc((size_t)512 * 256 * 2);
  u16* w0f_hh   = (u16*)alloc((size_t)512 * 128 * 2);
  u16* w0b_hh   = (u16*)alloc((size_t)512 * 128 * 2);
  u16* w1f_hh   = (u16*)alloc((size_t)512 * 128 * 2);
  u16* w1b_hh   = (u16*)alloc((size_t)512 * 128 * 2);
  u16* wfc1     = (u16*)alloc((size_t)256 * 1024 * 2);
  u16* wattn_bf = (u16*)alloc((size_t)4 * 256 * 256 * 2);
  u16* wlin0_bf = (u16*)alloc((size_t)4 * 256 * 256 * 2);
  u16* wlin1_bf = (u16*)alloc((size_t)4 * 256 * 256 * 2);
  u16* wlinf_bf = (u16*)alloc((size_t)256 * 256 * 2);
  float* bias4  = (float*)alloc((size_t)2048 * 4);
  float* X0f    = (float*)alloc((size_t)S_ * 16 * 512 * 4);
  float* X0b    = (float*)alloc((size_t)S_ * 16 * 512 * 4);
  u16* h0       = (u16*)alloc((size_t)B_ * S_ * 256 * 2);
  u16* lstm_out = (u16*)alloc((size_t)B_ * S_ * 256 * 2);
  u16* gA       = (u16*)alloc((size_t)B_ * S_ * 256 * 2);
  u16* gB       = (u16*)alloc((size_t)B_ * S_ * 256 * 2);
  u16* qb       = (u16*)alloc((size_t)B_ * S_ * 256 * 2);
  u16* gT       = (u16*)alloc((size_t)B_ * S_ * 256 * 2);
  u16* t1       = (u16*)alloc((size_t)B_ * S_ * 256 * 2);
  u16* t2       = (u16*)alloc((size_t)B_ * S_ * 256 * 2);
  u16* abf      = (u16*)alloc((size_t)B_ * S_ * S_ * 2);
  float* rinv   = (float*)alloc((size_t)B_ * S_ * 4);

  hipMemsetAsync(flags, 0, 256, stream);

  // ---- conversions (14 segments) ----
  CvtSegs cs;
  int nb = 0, si = 0;
  auto seg = [&](const float* s, u16* d, int n) {
    cs.src[si] = (const float4*)s; cs.dst[si] = (short4*)d;
    cs.blk0[si] = nb; nb += (n / 4 + 255) / 256; ++si;
  };
  seg(x, x_bf, B_ * S_ * D_);
  seg(l0f_Wih, w0f_ih, 512 * 1024);
  seg(l0b_Wih, w0b_ih, 512 * 1024);
  seg(l1f_Wih, w1f_ih, 512 * 256);
  seg(l1b_Wih, w1b_ih, 512 * 256);
  seg(l0f_Whh, w0f_hh, 512 * 128);
  seg(l0b_Whh, w0b_hh, 512 * 128);
  seg(l1f_Whh, w1f_hh, 512 * 128);
  seg(l1b_Whh, w1b_hh, 512 * 128);
  seg(fc1_W, wfc1, 256 * 1024);
  seg(wattn_W, wattn_bf, 4 * 256 * 256);
  seg(lin0_W, wlin0_bf, 4 * 256 * 256);
  seg(lin1_W, wlin1_bf, 4 * 256 * 256);
  seg(linf_W, wlinf_bf, 256 * 256);
  for (int k = si; k <= 14; ++k) cs.blk0[k] = nb;
  cvt_multi<<<nb, 256, 0, stream>>>(cs);
  bias_prep<<<8, 256, 0, stream>>>(l0f_bih, l0f_bhh, l0b_bih, l0b_bhh,
                                   l1f_bih, l1f_bhh, l1b_bih, l1b_bhh, bias4);

  GatArgs ga;
  ga.xbf = x_bf; ga.wfc1 = wfc1; ga.fc1b = fc1_b;
  ga.wattn = wattn_bf; ga.wattnb = wattn_b;
  ga.wlin0 = wlin0_bf; ga.lin0b = lin0_b;
  ga.wlin1 = wlin1_bf; ga.lin1b = lin1_b;
  ga.wlinf = wlinf_bf; ga.linfb = linf_b;
  ga.adj = adj;
  ga.gA = gA; ga.gB = gB; ga.qb = qb; ga.gT = gT;
  ga.t1 = t1; ga.t2 = t2; ga.abf = abf; ga.rinv = rinv;
  ga.flags = flags;

  const int W = 496;   // worker blocks; grid = 8 + W = 504, all co-resident

  // ---- LSTM L0 projections, then scan0 + GAT part0 (fc1, layers 0-1) ----
  proj2<<<dim3(8, 128, 2), 256, 0, stream>>>(x_bf, w0f_ih, w0b_ih, bias4, X0f, X0b, 1024);
  scan_gat<<<8 + W, 512, 0, stream>>>(X0f, X0b, w0f_hh, w0b_hh, h0, ga, 0, W);
  // ---- LSTM L1 projections, then scan1 + GAT part1 (layers 2-3, linf) ----
  proj2<<<dim3(8, 128, 2), 256, 0, stream>>>(h0, w1f_ih, w1b_ih, bias4 + 1024, X0f, X0b, 256);
  scan_gat<<<8 + W, 512, 0, stream>>>(X0f, X0b, w1f_hh, w1b_hh, lstm_out, ga, 1, W);

  // ---- pool + head ----
  mean_cat<<<16, 256, 0, stream>>>(lstm_out, t2, (float*)d_out);
  head_kernel<<<1, 256, 0, stream>>>((const float*)d_out + 32,
                                     fcA_W, fcA_b, fcB_W, fcB_b, fcC_W, fcC_b,
                                     (float*)d_out);
}

// Round 14
// 1763.184 us; speedup vs baseline: 3.5893x; 3.5893x over previous
//
#include <hip/hip_runtime.h>
#include <stdint.h>

#define B_ 16
#define S_ 512
#define D_ 1024
#define H4 512
#define G_ 256

typedef unsigned short u16;
using short8 = __attribute__((ext_vector_type(8))) short;
using f32x4  = __attribute__((ext_vector_type(4))) float;

__device__ __forceinline__ u16 f2bf(float f){
  unsigned int u = __float_as_uint(f);
  u += 0x7fffu + ((u >> 16) & 1u);
  return (u16)(u >> 16);
}
__device__ __forceinline__ float bf2f(u16 h){
  return __uint_as_float(((unsigned int)h) << 16);
}

// ---------------- single-dispatch f32 -> bf16 convert over all segments ----------------
struct CvtSegs {
  const float4* src[14];
  short4* dst[14];
  int blk0[15];
};
__global__ __launch_bounds__(256) void cvt_multi(CvtSegs cs){
  int blk = blockIdx.x;
  int s = 0;
  #pragma unroll
  for (int k = 0; k < 14; ++k) if (cs.blk0[k + 1] <= blk) s = k + 1;
  int i = (blk - cs.blk0[s]) * 256 + threadIdx.x;
  float4 v = cs.src[s][i];
  short4 o;
  o.x = (short)f2bf(v.x); o.y = (short)f2bf(v.y);
  o.z = (short)f2bf(v.z); o.w = (short)f2bf(v.w);
  cs.dst[s][i] = o;
}

// ---------------- LSTM bias sums (bih+bhh) ----------------
__global__ __launch_bounds__(256) void bias_prep(const float* a,const float* b,const float* c,const float* d,
                                                 const float* e,const float* f,const float* g,const float* h,
                                                 float* out){
  int i = blockIdx.x * 256 + threadIdx.x;
  if (i >= 2048) return;
  int p = i >> 9, k = i & 511;
  const float* x1 = (p==0)?a:(p==1)?c:(p==2)?e:g;
  const float* x2 = (p==0)?b:(p==1)?d:(p==2)?f:h;
  out[i] = x1[k] + x2[k];
}

// ---------------- MFMA BT-GEMM body (256-lane slice, 64x64 tile) ----------------
// EPI: 0=none, 1=relu, 2=score-mask (sigmoid+adj+eye, ex=adj), 3=row-scale (ex=rinv)
// PERM: 0 = row-major out, 2 = gate-interleaved X layout
template<int EPI, bool OUT_BF16, int PERM, bool RESID>
__device__ __forceinline__ void gemm_bt_body(
    const u16* __restrict__ A, const u16* __restrict__ W,
    const float* __restrict__ bias, const u16* __restrict__ resid,
    const float* __restrict__ ex,
    void* __restrict__ outp, int M, int N, int K,
    long sA, long sW, long sO, int bx, int by, int bz, int tid)
{
  const u16* Ab = A + (long)bz * sA;
  const u16* Wb = W + (long)bz * sW;
  const int bm0 = by * 64, bn0 = bx * 64;
  const int l = tid & 63, wid = tid >> 6;
  const int wm = (wid >> 1) * 32, wn = (wid & 1) * 32;
  const int lr = l & 15, lk8 = (l >> 4) * 8;

  const f32x4 z4 = {0.f, 0.f, 0.f, 0.f};
  f32x4 acc[2][2] = {{z4, z4}, {z4, z4}};

  const u16* Ap0 = Ab + (long)(bm0 + wm + lr) * K + lk8;
  const u16* Wp0 = Wb + (long)(bn0 + wn + lr) * K + lk8;
  for (int k0 = 0; k0 < K; k0 += 32) {
    short8 a0 = *reinterpret_cast<const short8*>(Ap0 + k0);
    short8 a1 = *reinterpret_cast<const short8*>(Ap0 + (long)16 * K + k0);
    short8 b0 = *reinterpret_cast<const short8*>(Wp0 + k0);
    short8 b1 = *reinterpret_cast<const short8*>(Wp0 + (long)16 * K + k0);
    acc[0][0] = __builtin_amdgcn_mfma_f32_16x16x32_bf16(a0, b0, acc[0][0], 0, 0, 0);
    acc[0][1] = __builtin_amdgcn_mfma_f32_16x16x32_bf16(a0, b1, acc[0][1], 0, 0, 0);
    acc[1][0] = __builtin_amdgcn_mfma_f32_16x16x32_bf16(a1, b0, acc[1][0], 0, 0, 0);
    acc[1][1] = __builtin_amdgcn_mfma_f32_16x16x32_bf16(a1, b1, acc[1][1], 0, 0, 0);
  }
  #pragma unroll
  for (int mt = 0; mt < 2; ++mt)
  #pragma unroll
  for (int nt = 0; nt < 2; ++nt) {
    int n = bn0 + wn + 16 * nt + lr;
    float bv = bias ? bias[n] : 0.f;
    #pragma unroll
    for (int r = 0; r < 4; ++r) {
      int m = bm0 + wm + 16 * mt + (l >> 4) * 4 + r;
      float v = acc[mt][nt][r] + bv;
      if (EPI == 1) v = fmaxf(v, 0.f);
      if (EPI == 2) {
        float sg = __fdividef(1.f, 1.f + __expf(-v));
        v = (n == m) ? (sg + 1e-5f) : sg * ex[((long)bz * 512 + m) * 512 + n];
      }
      if (EPI == 3) v *= ex[(long)bz * 512 + m];
      if (RESID) v += bf2f(resid[(long)m * N + n]);
      long oi;
      if (PERM == 2) {
        int t = m & 511, b = m >> 9;
        oi = (long)((t * 16 + b) * 128 + (n & 127)) * 4 + (n >> 7);
      } else {
        oi = (long)bz * sO + (long)m * N + n;
      }
      if (OUT_BF16) ((u16*)outp)[oi] = f2bf(v);
      else          ((float*)outp)[oi] = v;
    }
  }
}

template<int EPI, bool OUT_BF16, int PERM, bool RESID>
__global__ __launch_bounds__(256) void gemm_bt(
    const u16* __restrict__ A, const u16* __restrict__ W,
    const float* __restrict__ bias, const u16* __restrict__ resid,
    const float* __restrict__ ex,
    void* __restrict__ outp, int M, int N, int K,
    long sA, long sW, long sO)
{
  gemm_bt_body<EPI, OUT_BF16, PERM, RESID>(A, W, bias, resid, ex, outp, M, N, K,
                                           sA, sW, sO, blockIdx.x, blockIdx.y, blockIdx.z,
                                           threadIdx.x);
}

// ---------------- fused f/b input projections (PERM2, f32 out) ----------------
__global__ __launch_bounds__(256) void proj2(
    const u16* __restrict__ A, const u16* __restrict__ W0, const u16* __restrict__ W1,
    const float* __restrict__ bias, float* __restrict__ O0, float* __restrict__ O1, int K)
{
  int z = blockIdx.z;
  gemm_bt_body<0, false, 2, false>(A, z ? W1 : W0, bias + z * 512, nullptr, nullptr,
                                   z ? O1 : O0, 8192, 512, K, 0, 0, 0,
                                   blockIdx.x, blockIdx.y, 0, threadIdx.x);
}

// ---------------- 8-wave BT-GEMM body (512 thr, 64x128 tile, bf16 out, bias) ----------------
__device__ __forceinline__ void gemm_bt_body8(
    const u16* __restrict__ A, const u16* __restrict__ W,
    const float* __restrict__ bias, u16* __restrict__ out,
    int N, int K, int bx, int by)
{
  const int bm0 = by * 64, bn0 = bx * 128;
  const int tid = threadIdx.x;
  const int l = tid & 63, wid = tid >> 6;
  const int wm = (wid >> 2) * 32, wn = (wid & 3) * 32;
  const int lr = l & 15, lk8 = (l >> 4) * 8;

  const f32x4 z4 = {0.f, 0.f, 0.f, 0.f};
  f32x4 acc[2][2] = {{z4, z4}, {z4, z4}};

  const u16* Ap0 = A + (long)(bm0 + wm + lr) * K + lk8;
  const u16* Wp0 = W + (long)(bn0 + wn + lr) * K + lk8;
  for (int k0 = 0; k0 < K; k0 += 32) {
    short8 a0 = *reinterpret_cast<const short8*>(Ap0 + k0);
    short8 a1 = *reinterpret_cast<const short8*>(Ap0 + (long)16 * K + k0);
    short8 b0 = *reinterpret_cast<const short8*>(Wp0 + k0);
    short8 b1 = *reinterpret_cast<const short8*>(Wp0 + (long)16 * K + k0);
    acc[0][0] = __builtin_amdgcn_mfma_f32_16x16x32_bf16(a0, b0, acc[0][0], 0, 0, 0);
    acc[0][1] = __builtin_amdgcn_mfma_f32_16x16x32_bf16(a0, b1, acc[0][1], 0, 0, 0);
    acc[1][0] = __builtin_amdgcn_mfma_f32_16x16x32_bf16(a1, b0, acc[1][0], 0, 0, 0);
    acc[1][1] = __builtin_amdgcn_mfma_f32_16x16x32_bf16(a1, b1, acc[1][1], 0, 0, 0);
  }
  #pragma unroll
  for (int mt = 0; mt < 2; ++mt)
  #pragma unroll
  for (int nt = 0; nt < 2; ++nt) {
    int n = bn0 + wn + 16 * nt + lr;
    float bv = bias[n];
    #pragma unroll
    for (int r = 0; r < 4; ++r) {
      int m = bm0 + wm + 16 * mt + (l >> 4) * 4 + r;
      out[(long)m * N + n] = f2bf(acc[mt][nt][r] + bv);
    }
  }
}

// ---------------- LSTM scan v10: 4 blocks (4-batch group), BOTH dirs per wave ----------------
// Two independent recurrences interleaved in each wave: latency chains overlap,
// one shared barrier per step-pair. In-register z quads + dense gates as in v9.
__device__ __forceinline__ void lstm_scan10_body(
    const float* __restrict__ Xf, const float* __restrict__ Xb,
    const u16* __restrict__ Whhf, const u16* __restrict__ Whhb,
    u16* __restrict__ Hout, int bat0)
{
  __shared__ __align__(16) u16 hbuf[2][2][16][136];   // [dir][parity][A-row][j] ~17KB

  const int tid = threadIdx.x;
  const int l = tid & 63, w = tid >> 6;
  const int lr = l & 15, lk = l >> 4;

  short8 wf[2][4][4];
  #pragma unroll
  for (int g = 0; g < 4; ++g)
    #pragma unroll
    for (int ks = 0; ks < 4; ++ks) {
      wf[0][g][ks] = *reinterpret_cast<const short8*>(
          Whhf + (g * 128 + 16 * w + lr) * 128 + 32 * ks + 8 * lk);
      wf[1][g][ks] = *reinterpret_cast<const short8*>(
          Whhb + (g * 128 + 16 * w + lr) * 128 + 32 * ks + 8 * lk);
    }

  for (int i = tid; i < 2 * 2 * 16 * 136; i += 512) ((u16*)hbuf)[i] = 0;

  float c0 = 0.f, c1 = 0.f;
  const f32x4 z4 = {0.f, 0.f, 0.f, 0.f};

  auto ldX = [&](int d, int t) -> float4 {
    int ta = d ? (S_ - 1 - t) : t;
    const float* X = d ? Xb : Xf;
    return *reinterpret_cast<const float4*>(
        X + (size_t)((ta * 16 + bat0 + lk) * 128 + 16 * w + lr) * 4);
  };
  float4 a0 = ldX(0, 0), a1 = ldX(0, 1), a2 = ldX(0, 2), a3;
  float4 b0 = ldX(1, 0), b1 = ldX(1, 1), b2 = ldX(1, 2), b3;
  __syncthreads();

  auto gates = [&](const f32x4 (&acc)[4], const float4& xc, float& c, int d, int t) {
    float zi = acc[0][0] + xc.x;
    float zf = acc[1][0] + xc.y;
    float zg = acc[2][0] + xc.z;
    float zo = acc[3][0] + xc.w;
    float si = __fdividef(1.f, 1.f + __expf(-zi));
    float sf = __fdividef(1.f, 1.f + __expf(-zf));
    float so = __fdividef(1.f, 1.f + __expf(-zo));
    float eg = __expf(2.f * zg);
    float tg = 1.f - __fdividef(2.f, eg + 1.f);
    c = sf * c + si * tg;
    float ec = __expf(2.f * c);
    float tc = 1.f - __fdividef(2.f, ec + 1.f);
    u16 hb = f2bf(so * tc);
    int ta = d ? (S_ - 1 - t) : t;
    hbuf[d][(t & 1) ^ 1][4 * lk][16 * w + lr] = hb;
    Hout[((size_t)(bat0 + lk) * S_ + ta) * 256 + d * 128 + 16 * w + lr] = hb;
  };

  auto step = [&](int t, float4& xc0, float4& xt0, float4& xc1, float4& xt1, int tload) {
    const int p = t & 1;
    short8 af0[4], af1[4];
    #pragma unroll
    for (int ks = 0; ks < 4; ++ks) {
      af0[ks] = *reinterpret_cast<const short8*>(&hbuf[0][p][lr][32 * ks + 8 * lk]);
      af1[ks] = *reinterpret_cast<const short8*>(&hbuf[1][p][lr][32 * ks + 8 * lk]);
    }
    f32x4 acc0[4] = {z4, z4, z4, z4};
    f32x4 acc1[4] = {z4, z4, z4, z4};
    #pragma unroll
    for (int g = 0; g < 4; ++g)
      #pragma unroll
      for (int ks = 0; ks < 4; ++ks) {
        acc0[g] = __builtin_amdgcn_mfma_f32_16x16x32_bf16(af0[ks], wf[0][g][ks], acc0[g], 0, 0, 0);
        acc1[g] = __builtin_amdgcn_mfma_f32_16x16x32_bf16(af1[ks], wf[1][g][ks], acc1[g], 0, 0, 0);
      }
    if (tload < S_) { xt0 = ldX(0, tload); xt1 = ldX(1, tload); }
    gates(acc0, xc0, c0, 0, t);
    gates(acc1, xc1, c1, 1, t);
    asm volatile("s_waitcnt lgkmcnt(0)" ::: "memory");
    __builtin_amdgcn_s_barrier();
  };

  for (int t = 0; t < S_; t += 4) {
    step(t,     a0, a3, b0, b3, t + 3);
    step(t + 1, a1, a0, b1, b0, t + 4);
    step(t + 2, a2, a1, b2, b1, t + 5);
    step(t + 3, a3, a2, b3, b2, t + 6);
  }
}

// ---------------- fused dispatch: blocks 0..3 = scan(batgrp, both dirs), blocks 4.. = BT-GEMM ----
__global__ __launch_bounds__(512, 1) void scan_fused(
    const float* __restrict__ Xf, const float* __restrict__ Xb,
    const u16* __restrict__ Whhf, const u16* __restrict__ Whhb,
    u16* __restrict__ Hout,
    const u16* __restrict__ gA, const u16* __restrict__ gW,
    const float* __restrict__ gb, u16* __restrict__ gOut, int gK)
{
  if (blockIdx.x < 4) {
    lstm_scan10_body(Xf, Xb, Whhf, Whhb, Hout, blockIdx.x * 4);
  } else {
    int bi = blockIdx.x - 4;
    gemm_bt_body8(gA, gW, gb, gOut, 256, gK, bi & 1, bi >> 1);
  }
}

// ---------------- transpose body + kernels ----------------
__device__ __forceinline__ void transpose_body(const u16* __restrict__ in, u16* __restrict__ out,
                                               int bz, int s0, int d0)
{
  __shared__ u16 tile[32][33];
  int tx = threadIdx.x & 31, ty = threadIdx.x >> 5;
  const u16* ip = in + (long)bz * 512 * 256;
  u16* op = out + (long)bz * 256 * 512;
  #pragma unroll
  for (int k = 0; k < 32; k += 8) tile[ty + k][tx] = ip[(long)(s0 + ty + k) * 256 + d0 + tx];
  __syncthreads();
  #pragma unroll
  for (int k = 0; k < 32; k += 8) op[(long)(d0 + ty + k) * 512 + s0 + tx] = tile[tx][ty + k];
}

__global__ __launch_bounds__(256) void transpose_g(const u16* __restrict__ in, u16* __restrict__ out)
{
  transpose_body(in, out, blockIdx.z, blockIdx.x * 32, blockIdx.y * 32);
}

// wattn GEMM (512 blocks) || transpose (2048 blocks), both read gcur
__global__ __launch_bounds__(256) void wattn_trans(
    const u16* __restrict__ gcur, const u16* __restrict__ wW, const float* __restrict__ wb,
    u16* __restrict__ qb, u16* __restrict__ gT)
{
  if (blockIdx.x < 512) {
    int b = blockIdx.x;
    gemm_bt_body<0, true, 0, false>(gcur, wW, wb, nullptr, nullptr, qb,
                                    8192, 256, 256, 0, 0, 0, b & 3, b >> 2, 0, threadIdx.x);
  } else {
    int b = blockIdx.x - 512;
    int bz = b >> 7, rem = b & 127;
    transpose_body(gcur, gT, bz, (rem & 15) * 32, (rem >> 4) * 32);
  }
}

// ---------------- row-sum reciprocal of masked scores ----------------
__global__ __launch_bounds__(256) void rowsum_inv(const u16* __restrict__ abf, float* __restrict__ rinv)
{
  int bz = blockIdx.y;
  int row = blockIdx.x * 4 + (threadIdx.x >> 6);
  int l = threadIdx.x & 63;
  short8 v = *reinterpret_cast<const short8*>(abf + ((size_t)bz * 512 + row) * 512 + l * 8);
  float s = 0.f;
  #pragma unroll
  for (int k = 0; k < 8; ++k) s += bf2f((u16)v[k]);
  #pragma unroll
  for (int off = 32; off; off >>= 1) s += __shfl_xor(s, off);
  if (l == 0) rinv[bz * 512 + row] = __fdividef(1.f, s);
}

// ---------------- coalesced mean over S of concat[lstm_out, g_final] ----------------
__global__ __launch_bounds__(256) void mean_cat(
    const u16* __restrict__ lstm, const u16* __restrict__ gf, float* __restrict__ dout)
{
  int b = blockIdx.x, tid = threadIdx.x;
  float sl = 0.f, sg = 0.f;
  for (int t = 0; t < 512; ++t) {
    sl += bf2f(lstm[((size_t)b * 512 + t) * 256 + tid]);
    sg += bf2f(gf[((size_t)b * 512 + t) * 256 + tid]);
  }
  dout[32 + b * 512 + tid]       = sl * (1.f / 512.f);
  dout[32 + b * 512 + 256 + tid] = sg * (1.f / 512.f);
}

// ---------------- head: fcA -> leaky -> fcB -> leaky -> fcC ----------------
__global__ __launch_bounds__(256) void head_kernel(
    const float* __restrict__ hidden,
    const float* __restrict__ fcA_W, const float* __restrict__ fcA_b,
    const float* __restrict__ fcB_W, const float* __restrict__ fcB_b,
    const float* __restrict__ fcC_W, const float* __restrict__ fcC_b,
    float* __restrict__ y)
{
  __shared__ float hb[16 * 512];
  __shared__ float ab[16 * 128];
  __shared__ float bb[16 * 32];
  int tid = threadIdx.x;
  for (int i = tid; i < 8192; i += 256) hb[i] = hidden[i];
  __syncthreads();
  for (int o = tid; o < 2048; o += 256) {
    int b = o >> 7, jj = o & 127;
    float acc = fcA_b[jj];
    const float* wrow = fcA_W + jj * 512;
    const float* hrow = hb + b * 512;
    for (int k = 0; k < 512; ++k) acc += hrow[k] * wrow[k];
    ab[o] = acc > 0.f ? acc : 0.1f * acc;
  }
  __syncthreads();
  for (int o = tid; o < 512; o += 256) {
    int b = o >> 5, jj = o & 31;
    float acc = fcB_b[jj];
    for (int k = 0; k < 128; ++k) acc += ab[b * 128 + k] * fcB_W[jj * 128 + k];
    bb[o] = acc > 0.f ? acc : 0.1f * acc;
  }
  __syncthreads();
  if (tid < 32) {
    int b = tid >> 1, jj = tid & 1;
    float acc = fcC_b[jj];
    for (int k = 0; k < 32; ++k) acc += bb[b * 32 + k] * fcC_W[jj * 32 + k];
    y[b * 2 + jj] = acc;
  }
}

extern "C" void kernel_launch(void* const* d_in, const int* in_sizes, int n_in,
                              void* d_out, int out_size, void* d_ws, size_t ws_size,
                              hipStream_t stream)
{
  const float* x       = (const float*)d_in[0];
  const float* adj     = (const float*)d_in[1];
  const float* l0f_Wih = (const float*)d_in[2];
  const float* l0f_Whh = (const float*)d_in[3];
  const float* l0f_bih = (const float*)d_in[4];
  const float* l0f_bhh = (const float*)d_in[5];
  const float* l0b_Wih = (const float*)d_in[6];
  const float* l0b_Whh = (const float*)d_in[7];
  const float* l0b_bih = (const float*)d_in[8];
  const float* l0b_bhh = (const float*)d_in[9];
  const float* l1f_Wih = (const float*)d_in[10];
  const float* l1f_Whh = (const float*)d_in[11];
  const float* l1f_bih = (const float*)d_in[12];
  const float* l1f_bhh = (const float*)d_in[13];
  const float* l1b_Wih = (const float*)d_in[14];
  const float* l1b_Whh = (const float*)d_in[15];
  const float* l1b_bih = (const float*)d_in[16];
  const float* l1b_bhh = (const float*)d_in[17];
  const float* fc1_W   = (const float*)d_in[18];
  const float* fc1_b   = (const float*)d_in[19];
  const float* wattn_W = (const float*)d_in[20];
  const float* wattn_b = (const float*)d_in[21];
  const float* lin0_W  = (const float*)d_in[22];
  const float* lin0_b  = (const float*)d_in[23];
  const float* lin1_W  = (const float*)d_in[24];
  const float* lin1_b  = (const float*)d_in[25];
  const float* linf_W  = (const float*)d_in[26];
  const float* linf_b  = (const float*)d_in[27];
  const float* fcA_W   = (const float*)d_in[28];
  const float* fcA_b   = (const float*)d_in[29];
  const float* fcB_W   = (const float*)d_in[30];
  const float* fcB_b   = (const float*)d_in[31];
  const float* fcC_W   = (const float*)d_in[32];
  const float* fcC_b   = (const float*)d_in[33];

  char* wp = (char*)d_ws;
  auto alloc = [&](size_t n) -> void* { void* p = wp; wp += (n + 255) & ~(size_t)255; return p; };

  u16* x_bf     = (u16*)alloc((size_t)B_ * S_ * D_ * 2);
  u16* w0f_ih   = (u16*)alloc((size_t)512 * 1024 * 2);
  u16* w0b_ih   = (u16*)alloc((size_t)512 * 1024 * 2);
  u16* w1f_ih   = (u16*)alloc((size_t)512 * 256 * 2);
  u16* w1b_ih   = (u16*)alloc((size_t)512 * 256 * 2);
  u16* w0f_hh   = (u16*)alloc((size_t)512 * 128 * 2);
  u16* w0b_hh   = (u16*)alloc((size_t)512 * 128 * 2);
  u16* w1f_hh   = (u16*)alloc((size_t)512 * 128 * 2);
  u16* w1b_hh   = (u16*)alloc((size_t)512 * 128 * 2);
  u16* wfc1     = (u16*)alloc((size_t)256 * 1024 * 2);
  u16* wattn_bf = (u16*)alloc((size_t)4 * 256 * 256 * 2);
  u16* wlin0_bf = (u16*)alloc((size_t)4 * 256 * 256 * 2);
  u16* wlin1_bf = (u16*)alloc((size_t)4 * 256 * 256 * 2);
  u16* wlinf_bf = (u16*)alloc((size_t)256 * 256 * 2);
  float* bias4  = (float*)alloc((size_t)2048 * 4);
  float* X0f    = (float*)alloc((size_t)S_ * 16 * 512 * 4);
  float* X0b    = (float*)alloc((size_t)S_ * 16 * 512 * 4);
  u16* h0       = (u16*)alloc((size_t)B_ * S_ * 256 * 2);
  u16* lstm_out = (u16*)alloc((size_t)B_ * S_ * 256 * 2);
  u16* gA       = (u16*)alloc((size_t)B_ * S_ * 256 * 2);
  u16* gB       = (u16*)alloc((size_t)B_ * S_ * 256 * 2);
  u16* qb       = (u16*)alloc((size_t)B_ * S_ * 256 * 2);
  u16* gT       = (u16*)alloc((size_t)B_ * S_ * 256 * 2);
  u16* t1       = (u16*)alloc((size_t)B_ * S_ * 256 * 2);
  u16* t2       = (u16*)alloc((size_t)B_ * S_ * 256 * 2);
  u16* abf      = (u16*)alloc((size_t)B_ * S_ * S_ * 2);
  float* rinv   = (float*)alloc((size_t)B_ * S_ * 4);

  // ---- conversions (14 segments) ----
  CvtSegs cs;
  int nb = 0, si = 0;
  auto seg = [&](const float* s, u16* d, int n) {
    cs.src[si] = (const float4*)s; cs.dst[si] = (short4*)d;
    cs.blk0[si] = nb; nb += (n / 4 + 255) / 256; ++si;
  };
  seg(x, x_bf, B_ * S_ * D_);
  seg(l0f_Wih, w0f_ih, 512 * 1024);
  seg(l0b_Wih, w0b_ih, 512 * 1024);
  seg(l1f_Wih, w1f_ih, 512 * 256);
  seg(l1b_Wih, w1b_ih, 512 * 256);
  seg(l0f_Whh, w0f_hh, 512 * 128);
  seg(l0b_Whh, w0b_hh, 512 * 128);
  seg(l1f_Whh, w1f_hh, 512 * 128);
  seg(l1b_Whh, w1b_hh, 512 * 128);
  seg(fc1_W, wfc1, 256 * 1024);
  seg(wattn_W, wattn_bf, 4 * 256 * 256);
  seg(lin0_W, wlin0_bf, 4 * 256 * 256);
  seg(lin1_W, wlin1_bf, 4 * 256 * 256);
  seg(linf_W, wlinf_bf, 256 * 256);
  for (int k = si; k <= 14; ++k) cs.blk0[k] = nb;
  cvt_multi<<<nb, 256, 0, stream>>>(cs);
  bias_prep<<<8, 256, 0, stream>>>(l0f_bih, l0f_bhh, l0b_bih, l0b_bhh,
                                   l1f_bih, l1f_bhh, l1b_bih, l1b_bhh, bias4);

  // ---- LSTM layer 0: fused f/b projections, then dual-dir scan (+fc1 GEMM fused) ----
  proj2<<<dim3(8, 128, 2), 256, 0, stream>>>(x_bf, w0f_ih, w0b_ih, bias4, X0f, X0b, 1024);
  scan_fused<<<4 + 256, 512, 0, stream>>>(X0f, X0b, w0f_hh, w0b_hh, h0,
                                          x_bf, wfc1, fc1_b, gA, 1024);
  // ---- LSTM layer 1 (+ GAT layer-0 wattn GEMM fused) ----
  proj2<<<dim3(8, 128, 2), 256, 0, stream>>>(h0, w1f_ih, w1b_ih, bias4 + 1024, X0f, X0b, 256);
  scan_fused<<<4 + 256, 512, 0, stream>>>(X0f, X0b, w1f_hh, w1b_hh, lstm_out,
                                          gA, wattn_bf, wattn_b, qb, 256);

  // ---- GAT (serial dispatches, R11 structure) ----
  u16* gcur = gA; u16* gnext = gB;
  for (int lyr = 0; lyr < 4; ++lyr) {
    if (lyr == 0)
      transpose_g<<<dim3(16, 8, 16), 256, 0, stream>>>(gcur, gT);
    else
      wattn_trans<<<512 + 2048, 256, 0, stream>>>(gcur, wattn_bf + lyr * 65536,
                                                  wattn_b + lyr * 256, qb, gT);
    gemm_bt<2, true, 0, false><<<dim3(8, 8, 16), 256, 0, stream>>>(
        qb, gcur, nullptr, nullptr, adj, abf, 512, 512, 256, 131072, 131072, 262144);
    rowsum_inv<<<dim3(128, 16), 256, 0, stream>>>(abf, rinv);
    gemm_bt<3, true, 0, false><<<dim3(4, 8, 16), 256, 0, stream>>>(
        abf, gT, nullptr, nullptr, rinv, t1, 512, 256, 512, 262144, 131072, 131072);
    gemm_bt<1, true, 0, false><<<dim3(4, 128, 1), 256, 0, stream>>>(
        t1, wlin0_bf + lyr * 65536, lin0_b + lyr * 256, nullptr, nullptr, t2, 8192, 256, 256, 0, 0, 0);
    gemm_bt<1, true, 0, true><<<dim3(4, 128, 1), 256, 0, stream>>>(
        t2, wlin1_bf + lyr * 65536, lin1_b + lyr * 256, gcur, nullptr, gnext, 8192, 256, 256, 0, 0, 0);
    u16* tmp = gcur; gcur = gnext; gnext = tmp;
  }
  gemm_bt<0, true, 0, false><<<dim3(4, 128, 1), 256, 0, stream>>>(
      gcur, wlinf_bf, linf_b, nullptr, nullptr, t2, 8192, 256, 256, 0, 0, 0);

  // ---- pool + head ----
  mean_cat<<<16, 256, 0, stream>>>(lstm_out, t2, (float*)d_out);
  head_kernel<<<1, 256, 0, stream>>>((const float*)d_out + 32,
                                     fcA_W, fcA_b, fcB_W, fcB_b, fcC_W, fcC_b,
                                     (float*)d_out);
}

// Round 15
// 1230.933 us; speedup vs baseline: 5.1413x; 1.4324x over previous
//
#include <hip/hip_runtime.h>
#include <stdint.h>

#define B_ 16
#define S_ 512
#define D_ 1024
#define H4 512
#define G_ 256

typedef unsigned short u16;
using short8 = __attribute__((ext_vector_type(8))) short;
using f32x4  = __attribute__((ext_vector_type(4))) float;

__device__ __forceinline__ u16 f2bf(float f){
  unsigned int u = __float_as_uint(f);
  u += 0x7fffu + ((u >> 16) & 1u);
  return (u16)(u >> 16);
}
__device__ __forceinline__ float bf2f(u16 h){
  return __uint_as_float(((unsigned int)h) << 16);
}

// ---------------- single-dispatch f32 -> bf16 convert over all segments ----------------
struct CvtSegs {
  const float4* src[14];
  short4* dst[14];
  int blk0[15];
};
__global__ __launch_bounds__(256) void cvt_multi(CvtSegs cs){
  int blk = blockIdx.x;
  int s = 0;
  #pragma unroll
  for (int k = 0; k < 14; ++k) if (cs.blk0[k + 1] <= blk) s = k + 1;
  int i = (blk - cs.blk0[s]) * 256 + threadIdx.x;
  float4 v = cs.src[s][i];
  short4 o;
  o.x = (short)f2bf(v.x); o.y = (short)f2bf(v.y);
  o.z = (short)f2bf(v.z); o.w = (short)f2bf(v.w);
  cs.dst[s][i] = o;
}

// ---------------- LSTM bias sums (bih+bhh) ----------------
__global__ __launch_bounds__(256) void bias_prep(const float* a,const float* b,const float* c,const float* d,
                                                 const float* e,const float* f,const float* g,const float* h,
                                                 float* out){
  int i = blockIdx.x * 256 + threadIdx.x;
  if (i >= 2048) return;
  int p = i >> 9, k = i & 511;
  const float* x1 = (p==0)?a:(p==1)?c:(p==2)?e:g;
  const float* x2 = (p==0)?b:(p==1)?d:(p==2)?f:h;
  out[i] = x1[k] + x2[k];
}

// ---------------- MFMA BT-GEMM body (256-lane slice, 64x64 tile) ----------------
// EPI: 0=none, 1=relu, 2=score-mask (sigmoid+adj+eye; ex=adj, aux=rsum atomic out),
//      3=row-divide (ex=rsum). PERM: 0 = row-major out, 2 = gate-interleaved X layout
template<int EPI, bool OUT_BF16, int PERM, bool RESID>
__device__ __forceinline__ void gemm_bt_body(
    const u16* __restrict__ A, const u16* __restrict__ W,
    const float* __restrict__ bias, const u16* __restrict__ resid,
    const float* __restrict__ ex, float* __restrict__ aux,
    void* __restrict__ outp, int M, int N, int K,
    long sA, long sW, long sO, int bx, int by, int bz, int tid)
{
  const u16* Ab = A + (long)bz * sA;
  const u16* Wb = W + (long)bz * sW;
  const int bm0 = by * 64, bn0 = bx * 64;
  const int l = tid & 63, wid = tid >> 6;
  const int wm = (wid >> 1) * 32, wn = (wid & 1) * 32;
  const int lr = l & 15, lk8 = (l >> 4) * 8;

  const f32x4 z4 = {0.f, 0.f, 0.f, 0.f};
  f32x4 acc[2][2] = {{z4, z4}, {z4, z4}};

  const u16* Ap0 = Ab + (long)(bm0 + wm + lr) * K + lk8;
  const u16* Wp0 = Wb + (long)(bn0 + wn + lr) * K + lk8;
  for (int k0 = 0; k0 < K; k0 += 32) {
    short8 a0 = *reinterpret_cast<const short8*>(Ap0 + k0);
    short8 a1 = *reinterpret_cast<const short8*>(Ap0 + (long)16 * K + k0);
    short8 b0 = *reinterpret_cast<const short8*>(Wp0 + k0);
    short8 b1 = *reinterpret_cast<const short8*>(Wp0 + (long)16 * K + k0);
    acc[0][0] = __builtin_amdgcn_mfma_f32_16x16x32_bf16(a0, b0, acc[0][0], 0, 0, 0);
    acc[0][1] = __builtin_amdgcn_mfma_f32_16x16x32_bf16(a0, b1, acc[0][1], 0, 0, 0);
    acc[1][0] = __builtin_amdgcn_mfma_f32_16x16x32_bf16(a1, b0, acc[1][0], 0, 0, 0);
    acc[1][1] = __builtin_amdgcn_mfma_f32_16x16x32_bf16(a1, b1, acc[1][1], 0, 0, 0);
  }
  float rp[2][4] = {{0.f,0.f,0.f,0.f},{0.f,0.f,0.f,0.f}};
  #pragma unroll
  for (int mt = 0; mt < 2; ++mt)
  #pragma unroll
  for (int nt = 0; nt < 2; ++nt) {
    int n = bn0 + wn + 16 * nt + lr;
    float bv = bias ? bias[n] : 0.f;
    #pragma unroll
    for (int r = 0; r < 4; ++r) {
      int m = bm0 + wm + 16 * mt + (l >> 4) * 4 + r;
      float v = acc[mt][nt][r] + bv;
      if (EPI == 1) v = fmaxf(v, 0.f);
      if (EPI == 2) {
        float sg = __fdividef(1.f, 1.f + __expf(-v));
        v = (n == m) ? (sg + 1e-5f) : sg * ex[((long)bz * 512 + m) * 512 + n];
        rp[mt][r] += v;
      }
      if (EPI == 3) v = __fdividef(v, ex[(long)bz * 512 + m]);
      if (RESID) v += bf2f(resid[(long)m * N + n]);
      long oi;
      if (PERM == 2) {
        int t = m & 511, b = m >> 9;
        oi = (long)((t * 16 + b) * 128 + (n & 127)) * 4 + (n >> 7);
      } else {
        oi = (long)bz * sO + (long)m * N + n;
      }
      if (OUT_BF16) ((u16*)outp)[oi] = f2bf(v);
      else          ((float*)outp)[oi] = v;
    }
  }
  if (EPI == 2) {
    #pragma unroll
    for (int mt = 0; mt < 2; ++mt)
    #pragma unroll
    for (int r = 0; r < 4; ++r) {
      float s = rp[mt][r];
      #pragma unroll
      for (int off = 1; off < 16; off <<= 1) s += __shfl_xor(s, off);
      if (lr == 0) {
        int m = bm0 + wm + 16 * mt + (l >> 4) * 4 + r;
        atomicAdd(&aux[(long)bz * 512 + m], s);
      }
    }
  }
}

template<int EPI, bool OUT_BF16, int PERM, bool RESID>
__global__ __launch_bounds__(256) void gemm_bt(
    const u16* __restrict__ A, const u16* __restrict__ W,
    const float* __restrict__ bias, const u16* __restrict__ resid,
    const float* __restrict__ ex, float* __restrict__ aux,
    void* __restrict__ outp, int M, int N, int K,
    long sA, long sW, long sO)
{
  gemm_bt_body<EPI, OUT_BF16, PERM, RESID>(A, W, bias, resid, ex, aux, outp, M, N, K,
                                           sA, sW, sO, blockIdx.x, blockIdx.y, blockIdx.z,
                                           threadIdx.x);
}

// ---------------- fused f/b input projections (PERM2, f32 out) ----------------
__global__ __launch_bounds__(256) void proj2(
    const u16* __restrict__ A, const u16* __restrict__ W0, const u16* __restrict__ W1,
    const float* __restrict__ bias, float* __restrict__ O0, float* __restrict__ O1, int K)
{
  int z = blockIdx.z;
  gemm_bt_body<0, false, 2, false>(A, z ? W1 : W0, bias + z * 512, nullptr, nullptr, nullptr,
                                   z ? O1 : O0, 8192, 512, K, 0, 0, 0,
                                   blockIdx.x, blockIdx.y, 0, threadIdx.x);
}

// ---------------- 8-wave BT-GEMM body (512 thr, 64x128 tile, bf16 out, bias) ----------------
__device__ __forceinline__ void gemm_bt_body8(
    const u16* __restrict__ A, const u16* __restrict__ W,
    const float* __restrict__ bias, u16* __restrict__ out,
    int N, int K, int bx, int by)
{
  const int bm0 = by * 64, bn0 = bx * 128;
  const int tid = threadIdx.x;
  const int l = tid & 63, wid = tid >> 6;
  const int wm = (wid >> 2) * 32, wn = (wid & 3) * 32;
  const int lr = l & 15, lk8 = (l >> 4) * 8;

  const f32x4 z4 = {0.f, 0.f, 0.f, 0.f};
  f32x4 acc[2][2] = {{z4, z4}, {z4, z4}};

  const u16* Ap0 = A + (long)(bm0 + wm + lr) * K + lk8;
  const u16* Wp0 = W + (long)(bn0 + wn + lr) * K + lk8;
  for (int k0 = 0; k0 < K; k0 += 32) {
    short8 a0 = *reinterpret_cast<const short8*>(Ap0 + k0);
    short8 a1 = *reinterpret_cast<const short8*>(Ap0 + (long)16 * K + k0);
    short8 b0 = *reinterpret_cast<const short8*>(Wp0 + k0);
    short8 b1 = *reinterpret_cast<const short8*>(Wp0 + (long)16 * K + k0);
    acc[0][0] = __builtin_amdgcn_mfma_f32_16x16x32_bf16(a0, b0, acc[0][0], 0, 0, 0);
    acc[0][1] = __builtin_amdgcn_mfma_f32_16x16x32_bf16(a0, b1, acc[0][1], 0, 0, 0);
    acc[1][0] = __builtin_amdgcn_mfma_f32_16x16x32_bf16(a1, b0, acc[1][0], 0, 0, 0);
    acc[1][1] = __builtin_amdgcn_mfma_f32_16x16x32_bf16(a1, b1, acc[1][1], 0, 0, 0);
  }
  #pragma unroll
  for (int mt = 0; mt < 2; ++mt)
  #pragma unroll
  for (int nt = 0; nt < 2; ++nt) {
    int n = bn0 + wn + 16 * nt + lr;
    float bv = bias[n];
    #pragma unroll
    for (int r = 0; r < 4; ++r) {
      int m = bm0 + wm + 16 * mt + (l >> 4) * 4 + r;
      out[(long)m * N + n] = f2bf(acc[mt][nt][r] + bv);
    }
  }
}

// ---------------- LSTM scan v9 (R11): 8 blocks (dir x 4-batch group), dense gates ----------------
__device__ __forceinline__ void lstm_scan9_body(
    const float* __restrict__ X, const u16* __restrict__ Whh,
    u16* __restrict__ Hout, int dir, int bat0)
{
  __shared__ __align__(16) u16 hbuf[2][16][136];

  const int tid = threadIdx.x;
  const int l = tid & 63, w = tid >> 6;
  const int lr = l & 15, lk = l >> 4;

  short8 bfrag[4][4];
  #pragma unroll
  for (int g = 0; g < 4; ++g)
    #pragma unroll
    for (int ks = 0; ks < 4; ++ks)
      bfrag[g][ks] = *reinterpret_cast<const short8*>(
          Whh + (g * 128 + 16 * w + lr) * 128 + 32 * ks + 8 * lk);

  for (int i = tid; i < 2 * 16 * 136; i += 512) ((u16*)hbuf)[i] = 0;

  float c = 0.f;
  const f32x4 z4 = {0.f, 0.f, 0.f, 0.f};

  auto ldX = [&](int t) -> float4 {
    int ta = dir ? (S_ - 1 - t) : t;
    return *reinterpret_cast<const float4*>(
        X + (size_t)((ta * 16 + bat0 + lk) * 128 + 16 * w + lr) * 4);
  };
  float4 xA = ldX(0), xB = ldX(1), xC = ldX(2), xD;
  __syncthreads();

  auto step = [&](int t, float4& xc, float4& xt, int tload) {
    const int p = t & 1;
    short8 af[4];
    #pragma unroll
    for (int ks = 0; ks < 4; ++ks)
      af[ks] = *reinterpret_cast<const short8*>(&hbuf[p][lr][32 * ks + 8 * lk]);
    f32x4 acc[4] = {z4, z4, z4, z4};
    #pragma unroll
    for (int g = 0; g < 4; ++g)
      #pragma unroll
      for (int ks = 0; ks < 4; ++ks)
        acc[g] = __builtin_amdgcn_mfma_f32_16x16x32_bf16(af[ks], bfrag[g][ks], acc[g], 0, 0, 0);
    if (tload < S_) xt = ldX(tload);
    float zi = acc[0][0] + xc.x;
    float zf = acc[1][0] + xc.y;
    float zg = acc[2][0] + xc.z;
    float zo = acc[3][0] + xc.w;
    float si = __fdividef(1.f, 1.f + __expf(-zi));
    float sf = __fdividef(1.f, 1.f + __expf(-zf));
    float so = __fdividef(1.f, 1.f + __expf(-zo));
    float eg = __expf(2.f * zg);
    float tg = 1.f - __fdividef(2.f, eg + 1.f);
    c = sf * c + si * tg;
    float ec = __expf(2.f * c);
    float tc = 1.f - __fdividef(2.f, ec + 1.f);
    u16 hb = f2bf(so * tc);
    int ta = dir ? (S_ - 1 - t) : t;
    hbuf[p ^ 1][4 * lk][16 * w + lr] = hb;
    Hout[((size_t)(bat0 + lk) * S_ + ta) * 256 + dir * 128 + 16 * w + lr] = hb;
    asm volatile("s_waitcnt lgkmcnt(0)" ::: "memory");
    __builtin_amdgcn_s_barrier();
  };

  for (int t = 0; t < S_; t += 4) {
    step(t,     xA, xD, t + 3);
    step(t + 1, xB, xA, t + 4);
    step(t + 2, xC, xB, t + 5);
    step(t + 3, xD, xC, t + 6);
  }
}

// ---------------- fused dispatch: blocks 0..7 = scan(dir,batgrp), blocks 8.. = BT-GEMM ----------------
__global__ __launch_bounds__(512, 1) void scan_fused(
    const float* __restrict__ Xf, const float* __restrict__ Xb,
    const u16* __restrict__ Whhf, const u16* __restrict__ Whhb,
    u16* __restrict__ Hout,
    const u16* __restrict__ gA, const u16* __restrict__ gW,
    const float* __restrict__ gb, u16* __restrict__ gOut, int gK)
{
  if (blockIdx.x < 8) {
    int dir = blockIdx.x & 1, bat0 = (blockIdx.x >> 1) * 4;
    lstm_scan9_body(dir ? Xb : Xf, dir ? Whhb : Whhf, Hout, dir, bat0);
  } else {
    int bi = blockIdx.x - 8;
    gemm_bt_body8(gA, gW, gb, gOut, 256, gK, bi & 1, bi >> 1);
  }
}

// ---------------- transpose body + kernels ----------------
__device__ __forceinline__ void transpose_body(const u16* __restrict__ in, u16* __restrict__ out,
                                               int bz, int s0, int d0)
{
  __shared__ u16 tile[32][33];
  int tx = threadIdx.x & 31, ty = threadIdx.x >> 5;
  const u16* ip = in + (long)bz * 512 * 256;
  u16* op = out + (long)bz * 256 * 512;
  #pragma unroll
  for (int k = 0; k < 32; k += 8) tile[ty + k][tx] = ip[(long)(s0 + ty + k) * 256 + d0 + tx];
  __syncthreads();
  #pragma unroll
  for (int k = 0; k < 32; k += 8) op[(long)(d0 + ty + k) * 512 + s0 + tx] = tile[tx][ty + k];
}

__global__ __launch_bounds__(256) void transpose_g(const u16* __restrict__ in, u16* __restrict__ out)
{
  transpose_body(in, out, blockIdx.z, blockIdx.x * 32, blockIdx.y * 32);
}

// wattn GEMM (512 blocks) || transpose (2048 blocks), both read gcur
__global__ __launch_bounds__(256) void wattn_trans(
    const u16* __restrict__ gcur, const u16* __restrict__ wW, const float* __restrict__ wb,
    u16* __restrict__ qb, u16* __restrict__ gT)
{
  if (blockIdx.x < 512) {
    int b = blockIdx.x;
    gemm_bt_body<0, true, 0, false>(gcur, wW, wb, nullptr, nullptr, nullptr, qb,
                                    8192, 256, 256, 0, 0, 0, b & 3, b >> 2, 0, threadIdx.x);
  } else {
    int b = blockIdx.x - 512;
    int bz = b >> 7, rem = b & 127;
    transpose_body(gcur, gT, bz, (rem & 15) * 32, (rem >> 4) * 32);
  }
}

// ---------------- coalesced mean over S of concat[lstm_out, g_final] ----------------
__global__ __launch_bounds__(256) void mean_cat(
    const u16* __restrict__ lstm, const u16* __restrict__ gf, float* __restrict__ dout)
{
  int b = blockIdx.x, tid = threadIdx.x;
  float sl = 0.f, sg = 0.f;
  for (int t = 0; t < 512; ++t) {
    sl += bf2f(lstm[((size_t)b * 512 + t) * 256 + tid]);
    sg += bf2f(gf[((size_t)b * 512 + t) * 256 + tid]);
  }
  dout[32 + b * 512 + tid]       = sl * (1.f / 512.f);
  dout[32 + b * 512 + 256 + tid] = sg * (1.f / 512.f);
}

// ---------------- head: fcA -> leaky -> fcB -> leaky -> fcC ----------------
__global__ __launch_bounds__(256) void head_kernel(
    const float* __restrict__ hidden,
    const float* __restrict__ fcA_W, const float* __restrict__ fcA_b,
    const float* __restrict__ fcB_W, const float* __restrict__ fcB_b,
    const float* __restrict__ fcC_W, const float* __restrict__ fcC_b,
    float* __restrict__ y)
{
  __shared__ float hb[16 * 512];
  __shared__ float ab[16 * 128];
  __shared__ float bb[16 * 32];
  int tid = threadIdx.x;
  for (int i = tid; i < 8192; i += 256) hb[i] = hidden[i];
  __syncthreads();
  for (int o = tid; o < 2048; o += 256) {
    int b = o >> 7, jj = o & 127;
    float acc = fcA_b[jj];
    const float* wrow = fcA_W + jj * 512;
    const float* hrow = hb + b * 512;
    for (int k = 0; k < 512; ++k) acc += hrow[k] * wrow[k];
    ab[o] = acc > 0.f ? acc : 0.1f * acc;
  }
  __syncthreads();
  for (int o = tid; o < 512; o += 256) {
    int b = o >> 5, jj = o & 31;
    float acc = fcB_b[jj];
    for (int k = 0; k < 128; ++k) acc += ab[b * 128 + k] * fcB_W[jj * 128 + k];
    bb[o] = acc > 0.f ? acc : 0.1f * acc;
  }
  __syncthreads();
  if (tid < 32) {
    int b = tid >> 1, jj = tid & 1;
    float acc = fcC_b[jj];
    for (int k = 0; k < 32; ++k) acc += bb[b * 32 + k] * fcC_W[jj * 32 + k];
    y[b * 2 + jj] = acc;
  }
}

extern "C" void kernel_launch(void* const* d_in, const int* in_sizes, int n_in,
                              void* d_out, int out_size, void* d_ws, size_t ws_size,
                              hipStream_t stream)
{
  const float* x       = (const float*)d_in[0];
  const float* adj     = (const float*)d_in[1];
  const float* l0f_Wih = (const float*)d_in[2];
  const float* l0f_Whh = (const float*)d_in[3];
  const float* l0f_bih = (const float*)d_in[4];
  const float* l0f_bhh = (const float*)d_in[5];
  const float* l0b_Wih = (const float*)d_in[6];
  const float* l0b_Whh = (const float*)d_in[7];
  const float* l0b_bih = (const float*)d_in[8];
  const float* l0b_bhh = (const float*)d_in[9];
  const float* l1f_Wih = (const float*)d_in[10];
  const float* l1f_Whh = (const float*)d_in[11];
  const float* l1f_bih = (const float*)d_in[12];
  const float* l1f_bhh = (const float*)d_in[13];
  const float* l1b_Wih = (const float*)d_in[14];
  const float* l1b_Whh = (const float*)d_in[15];
  const float* l1b_bih = (const float*)d_in[16];
  const float* l1b_bhh = (const float*)d_in[17];
  const float* fc1_W   = (const float*)d_in[18];
  const float* fc1_b   = (const float*)d_in[19];
  const float* wattn_W = (const float*)d_in[20];
  const float* wattn_b = (const float*)d_in[21];
  const float* lin0_W  = (const float*)d_in[22];
  const float* lin0_b  = (const float*)d_in[23];
  const float* lin1_W  = (const float*)d_in[24];
  const float* lin1_b  = (const float*)d_in[25];
  const float* linf_W  = (const float*)d_in[26];
  const float* linf_b  = (const float*)d_in[27];
  const float* fcA_W   = (const float*)d_in[28];
  const float* fcA_b   = (const float*)d_in[29];
  const float* fcB_W   = (const float*)d_in[30];
  const float* fcB_b   = (const float*)d_in[31];
  const float* fcC_W   = (const float*)d_in[32];
  const float* fcC_b   = (const float*)d_in[33];

  char* wp = (char*)d_ws;
  auto alloc = [&](size_t n) -> void* { void* p = wp; wp += (n + 255) & ~(size_t)255; return p; };

  u16* x_bf     = (u16*)alloc((size_t)B_ * S_ * D_ * 2);
  u16* w0f_ih   = (u16*)alloc((size_t)512 * 1024 * 2);
  u16* w0b_ih   = (u16*)alloc((size_t)512 * 1024 * 2);
  u16* w1f_ih   = (u16*)alloc((size_t)512 * 256 * 2);
  u16* w1b_ih   = (u16*)alloc((size_t)512 * 256 * 2);
  u16* w0f_hh   = (u16*)alloc((size_t)512 * 128 * 2);
  u16* w0b_hh   = (u16*)alloc((size_t)512 * 128 * 2);
  u16* w1f_hh   = (u16*)alloc((size_t)512 * 128 * 2);
  u16* w1b_hh   = (u16*)alloc((size_t)512 * 128 * 2);
  u16* wfc1     = (u16*)alloc((size_t)256 * 1024 * 2);
  u16* wattn_bf = (u16*)alloc((size_t)4 * 256 * 256 * 2);
  u16* wlin0_bf = (u16*)alloc((size_t)4 * 256 * 256 * 2);
  u16* wlin1_bf = (u16*)alloc((size_t)4 * 256 * 256 * 2);
  u16* wlinf_bf = (u16*)alloc((size_t)256 * 256 * 2);
  float* bias4  = (float*)alloc((size_t)2048 * 4);
  float* X0f    = (float*)alloc((size_t)S_ * 16 * 512 * 4);
  float* X0b    = (float*)alloc((size_t)S_ * 16 * 512 * 4);
  u16* h0       = (u16*)alloc((size_t)B_ * S_ * 256 * 2);
  u16* lstm_out = (u16*)alloc((size_t)B_ * S_ * 256 * 2);
  u16* gA       = (u16*)alloc((size_t)B_ * S_ * 256 * 2);
  u16* gB       = (u16*)alloc((size_t)B_ * S_ * 256 * 2);
  u16* qb       = (u16*)alloc((size_t)B_ * S_ * 256 * 2);
  u16* gT       = (u16*)alloc((size_t)B_ * S_ * 256 * 2);
  u16* t1       = (u16*)alloc((size_t)B_ * S_ * 256 * 2);
  u16* t2       = (u16*)alloc((size_t)B_ * S_ * 256 * 2);
  u16* abf      = (u16*)alloc((size_t)B_ * S_ * S_ * 2);
  float* rsum   = (float*)alloc((size_t)B_ * S_ * 4);

  // ---- conversions (14 segments) ----
  CvtSegs cs;
  int nb = 0, si = 0;
  auto seg = [&](const float* s, u16* d, int n) {
    cs.src[si] = (const float4*)s; cs.dst[si] = (short4*)d;
    cs.blk0[si] = nb; nb += (n / 4 + 255) / 256; ++si;
  };
  seg(x, x_bf, B_ * S_ * D_);
  seg(l0f_Wih, w0f_ih, 512 * 1024);
  seg(l0b_Wih, w0b_ih, 512 * 1024);
  seg(l1f_Wih, w1f_ih, 512 * 256);
  seg(l1b_Wih, w1b_ih, 512 * 256);
  seg(l0f_Whh, w0f_hh, 512 * 128);
  seg(l0b_Whh, w0b_hh, 512 * 128);
  seg(l1f_Whh, w1f_hh, 512 * 128);
  seg(l1b_Whh, w1b_hh, 512 * 128);
  seg(fc1_W, wfc1, 256 * 1024);
  seg(wattn_W, wattn_bf, 4 * 256 * 256);
  seg(lin0_W, wlin0_bf, 4 * 256 * 256);
  seg(lin1_W, wlin1_bf, 4 * 256 * 256);
  seg(linf_W, wlinf_bf, 256 * 256);
  for (int k = si; k <= 14; ++k) cs.blk0[k] = nb;
  cvt_multi<<<nb, 256, 0, stream>>>(cs);
  bias_prep<<<8, 256, 0, stream>>>(l0f_bih, l0f_bhh, l0b_bih, l0b_bhh,
                                   l1f_bih, l1f_bhh, l1b_bih, l1b_bhh, bias4);

  // ---- LSTM layer 0: fused f/b projections, then scan (+fc1 GEMM fused) ----
  proj2<<<dim3(8, 128, 2), 256, 0, stream>>>(x_bf, w0f_ih, w0b_ih, bias4, X0f, X0b, 1024);
  scan_fused<<<8 + 256, 512, 0, stream>>>(X0f, X0b, w0f_hh, w0b_hh, h0,
                                          x_bf, wfc1, fc1_b, gA, 1024);
  // ---- LSTM layer 1 (+ GAT layer-0 wattn GEMM fused) ----
  proj2<<<dim3(8, 128, 2), 256, 0, stream>>>(h0, w1f_ih, w1b_ih, bias4 + 1024, X0f, X0b, 256);
  scan_fused<<<8 + 256, 512, 0, stream>>>(X0f, X0b, w1f_hh, w1b_hh, lstm_out,
                                          gA, wattn_bf, wattn_b, qb, 256);

  // ---- GAT (serial dispatches; rowsum fused into score epilogue via atomics) ----
  u16* gcur = gA; u16* gnext = gB;
  for (int lyr = 0; lyr < 4; ++lyr) {
    if (lyr == 0)
      transpose_g<<<dim3(16, 8, 16), 256, 0, stream>>>(gcur, gT);
    else
      wattn_trans<<<512 + 2048, 256, 0, stream>>>(gcur, wattn_bf + lyr * 65536,
                                                  wattn_b + lyr * 256, qb, gT);
    hipMemsetAsync(rsum, 0, (size_t)B_ * S_ * 4, stream);
    gemm_bt<2, true, 0, false><<<dim3(8, 8, 16), 256, 0, stream>>>(
        qb, gcur, nullptr, nullptr, adj, rsum, abf, 512, 512, 256, 131072, 131072, 262144);
    gemm_bt<3, true, 0, false><<<dim3(4, 8, 16), 256, 0, stream>>>(
        abf, gT, nullptr, nullptr, rsum, nullptr, t1, 512, 256, 512, 262144, 131072, 131072);
    gemm_bt<1, true, 0, false><<<dim3(4, 128, 1), 256, 0, stream>>>(
        t1, wlin0_bf + lyr * 65536, lin0_b + lyr * 256, nullptr, nullptr, nullptr, t2,
        8192, 256, 256, 0, 0, 0);
    gemm_bt<1, true, 0, true><<<dim3(4, 128, 1), 256, 0, stream>>>(
        t2, wlin1_bf + lyr * 65536, lin1_b + lyr * 256, gcur, nullptr, nullptr, gnext,
        8192, 256, 256, 0, 0, 0);
    u16* tmp = gcur; gcur = gnext; gnext = tmp;
  }
  gemm_bt<0, true, 0, false><<<dim3(4, 128, 1), 256, 0, stream>>>(
      gcur, wlinf_bf, linf_b, nullptr, nullptr, nullptr, t2, 8192, 256, 256, 0, 0, 0);

  // ---- pool + head ----
  mean_cat<<<16, 256, 0, stream>>>(lstm_out, t2, (float*)d_out);
  head_kernel<<<1, 256, 0, stream>>>((const float*)d_out + 32,
                                     fcA_W, fcA_b, fcB_W, fcB_b, fcC_W, fcC_b,
                                     (float*)d_out);
}

// Round 16
// 1230.493 us; speedup vs baseline: 5.1432x; 1.0004x over previous
//
#include <hip/hip_runtime.h>
#include <stdint.h>

#define B_ 16
#define S_ 512
#define D_ 1024
#define H4 512
#define G_ 256

typedef unsigned short u16;
using short8 = __attribute__((ext_vector_type(8))) short;
using f32x4  = __attribute__((ext_vector_type(4))) float;

__device__ __forceinline__ u16 f2bf(float f){
  unsigned int u = __float_as_uint(f);
  u += 0x7fffu + ((u >> 16) & 1u);
  return (u16)(u >> 16);
}
__device__ __forceinline__ float bf2f(u16 h){
  return __uint_as_float(((unsigned int)h) << 16);
}

// ---------------- single-dispatch f32 -> bf16 convert over all segments ----------------
struct CvtSegs {
  const float4* src[14];
  short4* dst[14];
  int blk0[15];
};
__global__ __launch_bounds__(256) void cvt_multi(CvtSegs cs){
  int blk = blockIdx.x;
  int s = 0;
  #pragma unroll
  for (int k = 0; k < 14; ++k) if (cs.blk0[k + 1] <= blk) s = k + 1;
  int i = (blk - cs.blk0[s]) * 256 + threadIdx.x;
  float4 v = cs.src[s][i];
  short4 o;
  o.x = (short)f2bf(v.x); o.y = (short)f2bf(v.y);
  o.z = (short)f2bf(v.z); o.w = (short)f2bf(v.w);
  cs.dst[s][i] = o;
}

// ---------------- LSTM bias sums (bih+bhh) ----------------
__global__ __launch_bounds__(256) void bias_prep(const float* a,const float* b,const float* c,const float* d,
                                                 const float* e,const float* f,const float* g,const float* h,
                                                 float* out){
  int i = blockIdx.x * 256 + threadIdx.x;
  if (i >= 2048) return;
  int p = i >> 9, k = i & 511;
  const float* x1 = (p==0)?a:(p==1)?c:(p==2)?e:g;
  const float* x2 = (p==0)?b:(p==1)?d:(p==2)?f:h;
  out[i] = x1[k] + x2[k];
}

// ---------------- MFMA BT-GEMM body (256-lane slice, 64x64 tile) ----------------
// EPI: 0=none, 1=relu, 2=score-mask (sigmoid+adj+eye; ex=adj, aux=rsum atomic out),
//      3=row-divide (ex=rsum). PERM: 0 = row-major out, 2 = gate-interleaved X layout
template<int EPI, bool OUT_BF16, int PERM, bool RESID>
__device__ __forceinline__ void gemm_bt_body(
    const u16* __restrict__ A, const u16* __restrict__ W,
    const float* __restrict__ bias, const u16* __restrict__ resid,
    const float* __restrict__ ex, float* __restrict__ aux,
    void* __restrict__ outp, int M, int N, int K,
    long sA, long sW, long sO, int bx, int by, int bz, int tid)
{
  const u16* Ab = A + (long)bz * sA;
  const u16* Wb = W + (long)bz * sW;
  const int bm0 = by * 64, bn0 = bx * 64;
  const int l = tid & 63, wid = tid >> 6;
  const int wm = (wid >> 1) * 32, wn = (wid & 1) * 32;
  const int lr = l & 15, lk8 = (l >> 4) * 8;

  const f32x4 z4 = {0.f, 0.f, 0.f, 0.f};
  f32x4 acc[2][2] = {{z4, z4}, {z4, z4}};

  const u16* Ap0 = Ab + (long)(bm0 + wm + lr) * K + lk8;
  const u16* Wp0 = Wb + (long)(bn0 + wn + lr) * K + lk8;
  for (int k0 = 0; k0 < K; k0 += 32) {
    short8 a0 = *reinterpret_cast<const short8*>(Ap0 + k0);
    short8 a1 = *reinterpret_cast<const short8*>(Ap0 + (long)16 * K + k0);
    short8 b0 = *reinterpret_cast<const short8*>(Wp0 + k0);
    short8 b1 = *reinterpret_cast<const short8*>(Wp0 + (long)16 * K + k0);
    acc[0][0] = __builtin_amdgcn_mfma_f32_16x16x32_bf16(a0, b0, acc[0][0], 0, 0, 0);
    acc[0][1] = __builtin_amdgcn_mfma_f32_16x16x32_bf16(a0, b1, acc[0][1], 0, 0, 0);
    acc[1][0] = __builtin_amdgcn_mfma_f32_16x16x32_bf16(a1, b0, acc[1][0], 0, 0, 0);
    acc[1][1] = __builtin_amdgcn_mfma_f32_16x16x32_bf16(a1, b1, acc[1][1], 0, 0, 0);
  }
  float rp[2][4] = {{0.f,0.f,0.f,0.f},{0.f,0.f,0.f,0.f}};
  #pragma unroll
  for (int mt = 0; mt < 2; ++mt)
  #pragma unroll
  for (int nt = 0; nt < 2; ++nt) {
    int n = bn0 + wn + 16 * nt + lr;
    float bv = bias ? bias[n] : 0.f;
    #pragma unroll
    for (int r = 0; r < 4; ++r) {
      int m = bm0 + wm + 16 * mt + (l >> 4) * 4 + r;
      float v = acc[mt][nt][r] + bv;
      if (EPI == 1) v = fmaxf(v, 0.f);
      if (EPI == 2) {
        float sg = __fdividef(1.f, 1.f + __expf(-v));
        v = (n == m) ? (sg + 1e-5f) : sg * ex[((long)bz * 512 + m) * 512 + n];
        rp[mt][r] += v;
      }
      if (EPI == 3) v = __fdividef(v, ex[(long)bz * 512 + m]);
      if (RESID) v += bf2f(resid[(long)m * N + n]);
      long oi;
      if (PERM == 2) {
        int t = m & 511, b = m >> 9;
        oi = (long)((t * 16 + b) * 128 + (n & 127)) * 4 + (n >> 7);
      } else {
        oi = (long)bz * sO + (long)m * N + n;
      }
      if (OUT_BF16) ((u16*)outp)[oi] = f2bf(v);
      else          ((float*)outp)[oi] = v;
    }
  }
  if (EPI == 2) {
    #pragma unroll
    for (int mt = 0; mt < 2; ++mt)
    #pragma unroll
    for (int r = 0; r < 4; ++r) {
      float s = rp[mt][r];
      #pragma unroll
      for (int off = 1; off < 16; off <<= 1) s += __shfl_xor(s, off);
      if (lr == 0) {
        int m = bm0 + wm + 16 * mt + (l >> 4) * 4 + r;
        atomicAdd(&aux[(long)bz * 512 + m], s);
      }
    }
  }
}

template<int EPI, bool OUT_BF16, int PERM, bool RESID>
__global__ __launch_bounds__(256) void gemm_bt(
    const u16* __restrict__ A, const u16* __restrict__ W,
    const float* __restrict__ bias, const u16* __restrict__ resid,
    const float* __restrict__ ex, float* __restrict__ aux,
    void* __restrict__ outp, int M, int N, int K,
    long sA, long sW, long sO)
{
  gemm_bt_body<EPI, OUT_BF16, PERM, RESID>(A, W, bias, resid, ex, aux, outp, M, N, K,
                                           sA, sW, sO, blockIdx.x, blockIdx.y, blockIdx.z,
                                           threadIdx.x);
}

// ---------------- fused f/b input projections (PERM2, f32 out) ----------------
__global__ __launch_bounds__(256) void proj2(
    const u16* __restrict__ A, const u16* __restrict__ W0, const u16* __restrict__ W1,
    const float* __restrict__ bias, float* __restrict__ O0, float* __restrict__ O1, int K)
{
  int z = blockIdx.z;
  gemm_bt_body<0, false, 2, false>(A, z ? W1 : W0, bias + z * 512, nullptr, nullptr, nullptr,
                                   z ? O1 : O0, 8192, 512, K, 0, 0, 0,
                                   blockIdx.x, blockIdx.y, 0, threadIdx.x);
}

// ---------------- 8-wave BT-GEMM body (512 thr, 64x128 tile, bf16 out, bias) ----------------
__device__ __forceinline__ void gemm_bt_body8(
    const u16* __restrict__ A, const u16* __restrict__ W,
    const float* __restrict__ bias, u16* __restrict__ out,
    int N, int K, int bx, int by)
{
  const int bm0 = by * 64, bn0 = bx * 128;
  const int tid = threadIdx.x;
  const int l = tid & 63, wid = tid >> 6;
  const int wm = (wid >> 2) * 32, wn = (wid & 3) * 32;
  const int lr = l & 15, lk8 = (l >> 4) * 8;

  const f32x4 z4 = {0.f, 0.f, 0.f, 0.f};
  f32x4 acc[2][2] = {{z4, z4}, {z4, z4}};

  const u16* Ap0 = A + (long)(bm0 + wm + lr) * K + lk8;
  const u16* Wp0 = W + (long)(bn0 + wn + lr) * K + lk8;
  for (int k0 = 0; k0 < K; k0 += 32) {
    short8 a0 = *reinterpret_cast<const short8*>(Ap0 + k0);
    short8 a1 = *reinterpret_cast<const short8*>(Ap0 + (long)16 * K + k0);
    short8 b0 = *reinterpret_cast<const short8*>(Wp0 + k0);
    short8 b1 = *reinterpret_cast<const short8*>(Wp0 + (long)16 * K + k0);
    acc[0][0] = __builtin_amdgcn_mfma_f32_16x16x32_bf16(a0, b0, acc[0][0], 0, 0, 0);
    acc[0][1] = __builtin_amdgcn_mfma_f32_16x16x32_bf16(a0, b1, acc[0][1], 0, 0, 0);
    acc[1][0] = __builtin_amdgcn_mfma_f32_16x16x32_bf16(a1, b0, acc[1][0], 0, 0, 0);
    acc[1][1] = __builtin_amdgcn_mfma_f32_16x16x32_bf16(a1, b1, acc[1][1], 0, 0, 0);
  }
  #pragma unroll
  for (int mt = 0; mt < 2; ++mt)
  #pragma unroll
  for (int nt = 0; nt < 2; ++nt) {
    int n = bn0 + wn + 16 * nt + lr;
    float bv = bias[n];
    #pragma unroll
    for (int r = 0; r < 4; ++r) {
      int m = bm0 + wm + 16 * mt + (l >> 4) * 4 + r;
      out[(long)m * N + n] = f2bf(acc[mt][nt][r] + bv);
    }
  }
}

// ---------------- LSTM scan v9.1: v9 + register-PINNED Whh fragments ----------------
// VGPR_Count was 60 => compiler was re-materializing the loop-invariant Whh loads from
// global every step (the hidden ~900cy/step). Empty asm "+v" makes them opaque live
// registers (rule #17 idiom), forcing true register residency.
__device__ __forceinline__ void lstm_scan9_body(
    const float* __restrict__ X, const u16* __restrict__ Whh,
    u16* __restrict__ Hout, int dir, int bat0)
{
  __shared__ __align__(16) u16 hbuf[2][16][136];

  const int tid = threadIdx.x;
  const int l = tid & 63, w = tid >> 6;
  const int lr = l & 15, lk = l >> 4;

  short8 bfrag[4][4];
  #pragma unroll
  for (int g = 0; g < 4; ++g)
    #pragma unroll
    for (int ks = 0; ks < 4; ++ks)
      bfrag[g][ks] = *reinterpret_cast<const short8*>(
          Whh + (g * 128 + 16 * w + lr) * 128 + 32 * ks + 8 * lk);
  // pin fragments in registers: opaque to the rematerializer
  #pragma unroll
  for (int g = 0; g < 4; ++g)
    #pragma unroll
    for (int ks = 0; ks < 4; ++ks)
      asm volatile("" : "+v"(bfrag[g][ks]));

  for (int i = tid; i < 2 * 16 * 136; i += 512) ((u16*)hbuf)[i] = 0;

  float c = 0.f;
  const f32x4 z4 = {0.f, 0.f, 0.f, 0.f};

  auto ldX = [&](int t) -> float4 {
    int ta = dir ? (S_ - 1 - t) : t;
    return *reinterpret_cast<const float4*>(
        X + (size_t)((ta * 16 + bat0 + lk) * 128 + 16 * w + lr) * 4);
  };
  float4 xA = ldX(0), xB = ldX(1), xC = ldX(2), xD;
  __syncthreads();

  auto step = [&](int t, float4& xc, float4& xt, int tload) {
    const int p = t & 1;
    short8 af[4];
    #pragma unroll
    for (int ks = 0; ks < 4; ++ks)
      af[ks] = *reinterpret_cast<const short8*>(&hbuf[p][lr][32 * ks + 8 * lk]);
    f32x4 acc[4] = {z4, z4, z4, z4};
    #pragma unroll
    for (int g = 0; g < 4; ++g)
      #pragma unroll
      for (int ks = 0; ks < 4; ++ks)
        acc[g] = __builtin_amdgcn_mfma_f32_16x16x32_bf16(af[ks], bfrag[g][ks], acc[g], 0, 0, 0);
    if (tload < S_) xt = ldX(tload);
    float zi = acc[0][0] + xc.x;
    float zf = acc[1][0] + xc.y;
    float zg = acc[2][0] + xc.z;
    float zo = acc[3][0] + xc.w;
    float si = __fdividef(1.f, 1.f + __expf(-zi));
    float sf = __fdividef(1.f, 1.f + __expf(-zf));
    float so = __fdividef(1.f, 1.f + __expf(-zo));
    float eg = __expf(2.f * zg);
    float tg = 1.f - __fdividef(2.f, eg + 1.f);
    c = sf * c + si * tg;
    float ec = __expf(2.f * c);
    float tc = 1.f - __fdividef(2.f, ec + 1.f);
    u16 hb = f2bf(so * tc);
    int ta = dir ? (S_ - 1 - t) : t;
    hbuf[p ^ 1][4 * lk][16 * w + lr] = hb;
    Hout[((size_t)(bat0 + lk) * S_ + ta) * 256 + dir * 128 + 16 * w + lr] = hb;
    asm volatile("s_waitcnt lgkmcnt(0)" ::: "memory");
    __builtin_amdgcn_s_barrier();
  };

  for (int t = 0; t < S_; t += 4) {
    step(t,     xA, xD, t + 3);
    step(t + 1, xB, xA, t + 4);
    step(t + 2, xC, xB, t + 5);
    step(t + 3, xD, xC, t + 6);
  }
}

// ---------------- fused dispatch: blocks 0..7 = scan(dir,batgrp), blocks 8.. = BT-GEMM ----------------
__global__ __launch_bounds__(512, 1) void scan_fused(
    const float* __restrict__ Xf, const float* __restrict__ Xb,
    const u16* __restrict__ Whhf, const u16* __restrict__ Whhb,
    u16* __restrict__ Hout,
    const u16* __restrict__ gA, const u16* __restrict__ gW,
    const float* __restrict__ gb, u16* __restrict__ gOut, int gK)
{
  if (blockIdx.x < 8) {
    int dir = blockIdx.x & 1, bat0 = (blockIdx.x >> 1) * 4;
    lstm_scan9_body(dir ? Xb : Xf, dir ? Whhb : Whhf, Hout, dir, bat0);
  } else {
    int bi = blockIdx.x - 8;
    gemm_bt_body8(gA, gW, gb, gOut, 256, gK, bi & 1, bi >> 1);
  }
}

// ---------------- transpose body + kernels ----------------
__device__ __forceinline__ void transpose_body(const u16* __restrict__ in, u16* __restrict__ out,
                                               int bz, int s0, int d0)
{
  __shared__ u16 tile[32][33];
  int tx = threadIdx.x & 31, ty = threadIdx.x >> 5;
  const u16* ip = in + (long)bz * 512 * 256;
  u16* op = out + (long)bz * 256 * 512;
  #pragma unroll
  for (int k = 0; k < 32; k += 8) tile[ty + k][tx] = ip[(long)(s0 + ty + k) * 256 + d0 + tx];
  __syncthreads();
  #pragma unroll
  for (int k = 0; k < 32; k += 8) op[(long)(d0 + ty + k) * 512 + s0 + tx] = tile[tx][ty + k];
}

__global__ __launch_bounds__(256) void transpose_g(const u16* __restrict__ in, u16* __restrict__ out)
{
  transpose_body(in, out, blockIdx.z, blockIdx.x * 32, blockIdx.y * 32);
}

// wattn GEMM (512 blocks) || transpose (2048 blocks), both read gcur
__global__ __launch_bounds__(256) void wattn_trans(
    const u16* __restrict__ gcur, const u16* __restrict__ wW, const float* __restrict__ wb,
    u16* __restrict__ qb, u16* __restrict__ gT)
{
  if (blockIdx.x < 512) {
    int b = blockIdx.x;
    gemm_bt_body<0, true, 0, false>(gcur, wW, wb, nullptr, nullptr, nullptr, qb,
                                    8192, 256, 256, 0, 0, 0, b & 3, b >> 2, 0, threadIdx.x);
  } else {
    int b = blockIdx.x - 512;
    int bz = b >> 7, rem = b & 127;
    transpose_body(gcur, gT, bz, (rem & 15) * 32, (rem >> 4) * 32);
  }
}

// ---------------- coalesced mean over S of concat[lstm_out, g_final] ----------------
__global__ __launch_bounds__(256) void mean_cat(
    const u16* __restrict__ lstm, const u16* __restrict__ gf, float* __restrict__ dout)
{
  int b = blockIdx.x, tid = threadIdx.x;
  float sl = 0.f, sg = 0.f;
  for (int t = 0; t < 512; ++t) {
    sl += bf2f(lstm[((size_t)b * 512 + t) * 256 + tid]);
    sg += bf2f(gf[((size_t)b * 512 + t) * 256 + tid]);
  }
  dout[32 + b * 512 + tid]       = sl * (1.f / 512.f);
  dout[32 + b * 512 + 256 + tid] = sg * (1.f / 512.f);
}

// ---------------- head: fcA -> leaky -> fcB -> leaky -> fcC ----------------
__global__ __launch_bounds__(256) void head_kernel(
    const float* __restrict__ hidden,
    const float* __restrict__ fcA_W, const float* __restrict__ fcA_b,
    const float* __restrict__ fcB_W, const float* __restrict__ fcB_b,
    const float* __restrict__ fcC_W, const float* __restrict__ fcC_b,
    float* __restrict__ y)
{
  __shared__ float hb[16 * 512];
  __shared__ float ab[16 * 128];
  __shared__ float bb[16 * 32];
  int tid = threadIdx.x;
  for (int i = tid; i < 8192; i += 256) hb[i] = hidden[i];
  __syncthreads();
  for (int o = tid; o < 2048; o += 256) {
    int b = o >> 7, jj = o & 127;
    float acc = fcA_b[jj];
    const float* wrow = fcA_W + jj * 512;
    const float* hrow = hb + b * 512;
    for (int k = 0; k < 512; ++k) acc += hrow[k] * wrow[k];
    ab[o] = acc > 0.f ? acc : 0.1f * acc;
  }
  __syncthreads();
  for (int o = tid; o < 512; o += 256) {
    int b = o >> 5, jj = o & 31;
    float acc = fcB_b[jj];
    for (int k = 0; k < 128; ++k) acc += ab[b * 128 + k] * fcB_W[jj * 128 + k];
    bb[o] = acc > 0.f ? acc : 0.1f * acc;
  }
  __syncthreads();
  if (tid < 32) {
    int b = tid >> 1, jj = tid & 1;
    float acc = fcC_b[jj];
    for (int k = 0; k < 32; ++k) acc += bb[b * 32 + k] * fcC_W[jj * 32 + k];
    y[b * 2 + jj] = acc;
  }
}

extern "C" void kernel_launch(void* const* d_in, const int* in_sizes, int n_in,
                              void* d_out, int out_size, void* d_ws, size_t ws_size,
                              hipStream_t stream)
{
  const float* x       = (const float*)d_in[0];
  const float* adj     = (const float*)d_in[1];
  const float* l0f_Wih = (const float*)d_in[2];
  const float* l0f_Whh = (const float*)d_in[3];
  const float* l0f_bih = (const float*)d_in[4];
  const float* l0f_bhh = (const float*)d_in[5];
  const float* l0b_Wih = (const float*)d_in[6];
  const float* l0b_Whh = (const float*)d_in[7];
  const float* l0b_bih = (const float*)d_in[8];
  const float* l0b_bhh = (const float*)d_in[9];
  const float* l1f_Wih = (const float*)d_in[10];
  const float* l1f_Whh = (const float*)d_in[11];
  const float* l1f_bih = (const float*)d_in[12];
  const float* l1f_bhh = (const float*)d_in[13];
  const float* l1b_Wih = (const float*)d_in[14];
  const float* l1b_Whh = (const float*)d_in[15];
  const float* l1b_bih = (const float*)d_in[16];
  const float* l1b_bhh = (const float*)d_in[17];
  const float* fc1_W   = (const float*)d_in[18];
  const float* fc1_b   = (const float*)d_in[19];
  const float* wattn_W = (const float*)d_in[20];
  const float* wattn_b = (const float*)d_in[21];
  const float* lin0_W  = (const float*)d_in[22];
  const float* lin0_b  = (const float*)d_in[23];
  const float* lin1_W  = (const float*)d_in[24];
  const float* lin1_b  = (const float*)d_in[25];
  const float* linf_W  = (const float*)d_in[26];
  const float* linf_b  = (const float*)d_in[27];
  const float* fcA_W   = (const float*)d_in[28];
  const float* fcA_b   = (const float*)d_in[29];
  const float* fcB_W   = (const float*)d_in[30];
  const float* fcB_b   = (const float*)d_in[31];
  const float* fcC_W   = (const float*)d_in[32];
  const float* fcC_b   = (const float*)d_in[33];

  char* wp = (char*)d_ws;
  auto alloc = [&](size_t n) -> void* { void* p = wp; wp += (n + 255) & ~(size_t)255; return p; };

  u16* x_bf     = (u16*)alloc((size_t)B_ * S_ * D_ * 2);
  u16* w0f_ih   = (u16*)alloc((size_t)512 * 1024 * 2);
  u16* w0b_ih   = (u16*)alloc((size_t)512 * 1024 * 2);
  u16* w1f_ih   = (u16*)alloc((size_t)512 * 256 * 2);
  u16* w1b_ih   = (u16*)alloc((size_t)512 * 256 * 2);
  u16* w0f_hh   = (u16*)alloc((size_t)512 * 128 * 2);
  u16* w0b_hh   = (u16*)alloc((size_t)512 * 128 * 2);
  u16* w1f_hh   = (u16*)alloc((size_t)512 * 128 * 2);
  u16* w1b_hh   = (u16*)alloc((size_t)512 * 128 * 2);
  u16* wfc1     = (u16*)alloc((size_t)256 * 1024 * 2);
  u16* wattn_bf = (u16*)alloc((size_t)4 * 256 * 256 * 2);
  u16* wlin0_bf = (u16*)alloc((size_t)4 * 256 * 256 * 2);
  u16* wlin1_bf = (u16*)alloc((size_t)4 * 256 * 256 * 2);
  u16* wlinf_bf = (u16*)alloc((size_t)256 * 256 * 2);
  float* bias4  = (float*)alloc((size_t)2048 * 4);
  float* X0f    = (float*)alloc((size_t)S_ * 16 * 512 * 4);
  float* X0b    = (float*)alloc((size_t)S_ * 16 * 512 * 4);
  u16* h0       = (u16*)alloc((size_t)B_ * S_ * 256 * 2);
  u16* lstm_out = (u16*)alloc((size_t)B_ * S_ * 256 * 2);
  u16* gA       = (u16*)alloc((size_t)B_ * S_ * 256 * 2);
  u16* gB       = (u16*)alloc((size_t)B_ * S_ * 256 * 2);
  u16* qb       = (u16*)alloc((size_t)B_ * S_ * 256 * 2);
  u16* gT       = (u16*)alloc((size_t)B_ * S_ * 256 * 2);
  u16* t1       = (u16*)alloc((size_t)B_ * S_ * 256 * 2);
  u16* t2       = (u16*)alloc((size_t)B_ * S_ * 256 * 2);
  u16* abf      = (u16*)alloc((size_t)B_ * S_ * S_ * 2);
  float* rsum   = (float*)alloc((size_t)B_ * S_ * 4);

  // ---- conversions (14 segments) ----
  CvtSegs cs;
  int nb = 0, si = 0;
  auto seg = [&](const float* s, u16* d, int n) {
    cs.src[si] = (const float4*)s; cs.dst[si] = (short4*)d;
    cs.blk0[si] = nb; nb += (n / 4 + 255) / 256; ++si;
  };
  seg(x, x_bf, B_ * S_ * D_);
  seg(l0f_Wih, w0f_ih, 512 * 1024);
  seg(l0b_Wih, w0b_ih, 512 * 1024);
  seg(l1f_Wih, w1f_ih, 512 * 256);
  seg(l1b_Wih, w1b_ih, 512 * 256);
  seg(l0f_Whh, w0f_hh, 512 * 128);
  seg(l0b_Whh, w0b_hh, 512 * 128);
  seg(l1f_Whh, w1f_hh, 512 * 128);
  seg(l1b_Whh, w1b_hh, 512 * 128);
  seg(fc1_W, wfc1, 256 * 1024);
  seg(wattn_W, wattn_bf, 4 * 256 * 256);
  seg(lin0_W, wlin0_bf, 4 * 256 * 256);
  seg(lin1_W, wlin1_bf, 4 * 256 * 256);
  seg(linf_W, wlinf_bf, 256 * 256);
  for (int k = si; k <= 14; ++k) cs.blk0[k] = nb;
  cvt_multi<<<nb, 256, 0, stream>>>(cs);
  bias_prep<<<8, 256, 0, stream>>>(l0f_bih, l0f_bhh, l0b_bih, l0b_bhh,
                                   l1f_bih, l1f_bhh, l1b_bih, l1b_bhh, bias4);

  // ---- LSTM layer 0: fused f/b projections, then scan (+fc1 GEMM fused) ----
  proj2<<<dim3(8, 128, 2), 256, 0, stream>>>(x_bf, w0f_ih, w0b_ih, bias4, X0f, X0b, 1024);
  scan_fused<<<8 + 256, 512, 0, stream>>>(X0f, X0b, w0f_hh, w0b_hh, h0,
                                          x_bf, wfc1, fc1_b, gA, 1024);
  // ---- LSTM layer 1 (+ GAT layer-0 wattn GEMM fused) ----
  proj2<<<dim3(8, 128, 2), 256, 0, stream>>>(h0, w1f_ih, w1b_ih, bias4 + 1024, X0f, X0b, 256);
  scan_fused<<<8 + 256, 512, 0, stream>>>(X0f, X0b, w1f_hh, w1b_hh, lstm_out,
                                          gA, wattn_bf, wattn_b, qb, 256);

  // ---- GAT (serial dispatches; rowsum fused into score epilogue via atomics) ----
  u16* gcur = gA; u16* gnext = gB;
  for (int lyr = 0; lyr < 4; ++lyr) {
    if (lyr == 0)
      transpose_g<<<dim3(16, 8, 16), 256, 0, stream>>>(gcur, gT);
    else
      wattn_trans<<<512 + 2048, 256, 0, stream>>>(gcur, wattn_bf + lyr * 65536,
                                                  wattn_b + lyr * 256, qb, gT);
    hipMemsetAsync(rsum, 0, (size_t)B_ * S_ * 4, stream);
    gemm_bt<2, true, 0, false><<<dim3(8, 8, 16), 256, 0, stream>>>(
        qb, gcur, nullptr, nullptr, adj, rsum, abf, 512, 512, 256, 131072, 131072, 262144);
    gemm_bt<3, true, 0, false><<<dim3(4, 8, 16), 256, 0, stream>>>(
        abf, gT, nullptr, nullptr, rsum, nullptr, t1, 512, 256, 512, 262144, 131072, 131072);
    gemm_bt<1, true, 0, false><<<dim3(4, 128, 1), 256, 0, stream>>>(
        t1, wlin0_bf + lyr * 65536, lin0_b + lyr * 256, nullptr, nullptr, nullptr, t2,
        8192, 256, 256, 0, 0, 0);
    gemm_bt<1, true, 0, true><<<dim3(4, 128, 1), 256, 0, stream>>>(
        t2, wlin1_bf + lyr * 65536, lin1_b + lyr * 256, gcur, nullptr, nullptr, gnext,
        8192, 256, 256, 0, 0, 0);
    u16* tmp = gcur; gcur = gnext; gnext = tmp;
  }
  gemm_bt<0, true, 0, false><<<dim3(4, 128, 1), 256, 0, stream>>>(
      gcur, wlinf_bf, linf_b, nullptr, nullptr, nullptr, t2, 8192, 256, 256, 0, 0, 0);

  // ---- pool + head ----
  mean_cat<<<16, 256, 0, stream>>>(lstm_out, t2, (float*)d_out);
  head_kernel<<<1, 256, 0, stream>>>((const float*)d_out + 32,
                                     fcA_W, fcA_b, fcB_W, fcB_b, fcC_W, fcC_b,
                                     (float*)d_out);
}

// Round 17
// 1212.818 us; speedup vs baseline: 5.2181x; 1.0146x over previous
//
#include <hip/hip_runtime.h>
#include <stdint.h>

#define B_ 16
#define S_ 512
#define D_ 1024
#define H4 512
#define G_ 256

typedef unsigned short u16;
using short8 = __attribute__((ext_vector_type(8))) short;
using f32x4  = __attribute__((ext_vector_type(4))) float;

__device__ __forceinline__ u16 f2bf(float f){
  unsigned int u = __float_as_uint(f);
  u += 0x7fffu + ((u >> 16) & 1u);
  return (u16)(u >> 16);
}
__device__ __forceinline__ float bf2f(u16 h){
  return __uint_as_float(((unsigned int)h) << 16);
}

// ---------------- single-dispatch f32 -> bf16 convert over all segments ----------------
struct CvtSegs {
  const float4* src[14];
  short4* dst[14];
  int blk0[15];
};
__global__ __launch_bounds__(256) void cvt_multi(CvtSegs cs){
  int blk = blockIdx.x;
  int s = 0;
  #pragma unroll
  for (int k = 0; k < 14; ++k) if (cs.blk0[k + 1] <= blk) s = k + 1;
  int i = (blk - cs.blk0[s]) * 256 + threadIdx.x;
  float4 v = cs.src[s][i];
  short4 o;
  o.x = (short)f2bf(v.x); o.y = (short)f2bf(v.y);
  o.z = (short)f2bf(v.z); o.w = (short)f2bf(v.w);
  cs.dst[s][i] = o;
}

// ---------------- LSTM bias sums (bih+bhh) ----------------
__global__ __launch_bounds__(256) void bias_prep(const float* a,const float* b,const float* c,const float* d,
                                                 const float* e,const float* f,const float* g,const float* h,
                                                 float* out){
  int i = blockIdx.x * 256 + threadIdx.x;
  if (i >= 2048) return;
  int p = i >> 9, k = i & 511;
  const float* x1 = (p==0)?a:(p==1)?c:(p==2)?e:g;
  const float* x2 = (p==0)?b:(p==1)?d:(p==2)?f:h;
  out[i] = x1[k] + x2[k];
}

// ---------------- MFMA BT-GEMM body (256-lane slice, 64x64 tile) ----------------
// EPI: 0=none, 1=relu, 2=score-mask (sigmoid+adj+eye; ex=adj, aux=rsum atomic out),
//      3=row-divide (ex=rsum). PERM: 0 = row-major out, 2 = gate-interleaved X layout
template<int EPI, bool OUT_BF16, int PERM, bool RESID>
__device__ __forceinline__ void gemm_bt_body(
    const u16* __restrict__ A, const u16* __restrict__ W,
    const float* __restrict__ bias, const u16* __restrict__ resid,
    const float* __restrict__ ex, float* __restrict__ aux,
    void* __restrict__ outp, int M, int N, int K,
    long sA, long sW, long sO, int bx, int by, int bz, int tid)
{
  const u16* Ab = A + (long)bz * sA;
  const u16* Wb = W + (long)bz * sW;
  const int bm0 = by * 64, bn0 = bx * 64;
  const int l = tid & 63, wid = tid >> 6;
  const int wm = (wid >> 1) * 32, wn = (wid & 1) * 32;
  const int lr = l & 15, lk8 = (l >> 4) * 8;

  const f32x4 z4 = {0.f, 0.f, 0.f, 0.f};
  f32x4 acc[2][2] = {{z4, z4}, {z4, z4}};

  const u16* Ap0 = Ab + (long)(bm0 + wm + lr) * K + lk8;
  const u16* Wp0 = Wb + (long)(bn0 + wn + lr) * K + lk8;
  for (int k0 = 0; k0 < K; k0 += 32) {
    short8 a0 = *reinterpret_cast<const short8*>(Ap0 + k0);
    short8 a1 = *reinterpret_cast<const short8*>(Ap0 + (long)16 * K + k0);
    short8 b0 = *reinterpret_cast<const short8*>(Wp0 + k0);
    short8 b1 = *reinterpret_cast<const short8*>(Wp0 + (long)16 * K + k0);
    acc[0][0] = __builtin_amdgcn_mfma_f32_16x16x32_bf16(a0, b0, acc[0][0], 0, 0, 0);
    acc[0][1] = __builtin_amdgcn_mfma_f32_16x16x32_bf16(a0, b1, acc[0][1], 0, 0, 0);
    acc[1][0] = __builtin_amdgcn_mfma_f32_16x16x32_bf16(a1, b0, acc[1][0], 0, 0, 0);
    acc[1][1] = __builtin_amdgcn_mfma_f32_16x16x32_bf16(a1, b1, acc[1][1], 0, 0, 0);
  }
  float rp[2][4] = {{0.f,0.f,0.f,0.f},{0.f,0.f,0.f,0.f}};
  #pragma unroll
  for (int mt = 0; mt < 2; ++mt)
  #pragma unroll
  for (int nt = 0; nt < 2; ++nt) {
    int n = bn0 + wn + 16 * nt + lr;
    float bv = bias ? bias[n] : 0.f;
    #pragma unroll
    for (int r = 0; r < 4; ++r) {
      int m = bm0 + wm + 16 * mt + (l >> 4) * 4 + r;
      float v = acc[mt][nt][r] + bv;
      if (EPI == 1) v = fmaxf(v, 0.f);
      if (EPI == 2) {
        float sg = __fdividef(1.f, 1.f + __expf(-v));
        v = (n == m) ? (sg + 1e-5f) : sg * ex[((long)bz * 512 + m) * 512 + n];
        rp[mt][r] += v;
      }
      if (EPI == 3) v = __fdividef(v, ex[(long)bz * 512 + m]);
      if (RESID) v += bf2f(resid[(long)m * N + n]);
      long oi;
      if (PERM == 2) {
        int t = m & 511, b = m >> 9;
        oi = (long)((t * 16 + b) * 128 + (n & 127)) * 4 + (n >> 7);
      } else {
        oi = (long)bz * sO + (long)m * N + n;
      }
      if (OUT_BF16) ((u16*)outp)[oi] = f2bf(v);
      else          ((float*)outp)[oi] = v;
    }
  }
  if (EPI == 2) {
    #pragma unroll
    for (int mt = 0; mt < 2; ++mt)
    #pragma unroll
    for (int r = 0; r < 4; ++r) {
      float s = rp[mt][r];
      #pragma unroll
      for (int off = 1; off < 16; off <<= 1) s += __shfl_xor(s, off);
      if (lr == 0) {
        int m = bm0 + wm + 16 * mt + (l >> 4) * 4 + r;
        atomicAdd(&aux[(long)bz * 512 + m], s);
      }
    }
  }
}

template<int EPI, bool OUT_BF16, int PERM, bool RESID>
__global__ __launch_bounds__(256) void gemm_bt(
    const u16* __restrict__ A, const u16* __restrict__ W,
    const float* __restrict__ bias, const u16* __restrict__ resid,
    const float* __restrict__ ex, float* __restrict__ aux,
    void* __restrict__ outp, int M, int N, int K,
    long sA, long sW, long sO)
{
  gemm_bt_body<EPI, OUT_BF16, PERM, RESID>(A, W, bias, resid, ex, aux, outp, M, N, K,
                                           sA, sW, sO, blockIdx.x, blockIdx.y, blockIdx.z,
                                           threadIdx.x);
}

// ---------------- fused f/b input projections (PERM2, f32 out) ----------------
__global__ __launch_bounds__(256) void proj2(
    const u16* __restrict__ A, const u16* __restrict__ W0, const u16* __restrict__ W1,
    const float* __restrict__ bias, float* __restrict__ O0, float* __restrict__ O1, int K)
{
  int z = blockIdx.z;
  gemm_bt_body<0, false, 2, false>(A, z ? W1 : W0, bias + z * 512, nullptr, nullptr, nullptr,
                                   z ? O1 : O0, 8192, 512, K, 0, 0, 0,
                                   blockIdx.x, blockIdx.y, 0, threadIdx.x);
}

// ---------------- 8-wave BT-GEMM body (512 thr, 64x128 tile, bf16 out, bias) ----------------
__device__ __forceinline__ void gemm_bt_body8(
    const u16* __restrict__ A, const u16* __restrict__ W,
    const float* __restrict__ bias, u16* __restrict__ out,
    int N, int K, int bx, int by)
{
  const int bm0 = by * 64, bn0 = bx * 128;
  const int tid = threadIdx.x;
  const int l = tid & 63, wid = tid >> 6;
  const int wm = (wid >> 2) * 32, wn = (wid & 3) * 32;
  const int lr = l & 15, lk8 = (l >> 4) * 8;

  const f32x4 z4 = {0.f, 0.f, 0.f, 0.f};
  f32x4 acc[2][2] = {{z4, z4}, {z4, z4}};

  const u16* Ap0 = A + (long)(bm0 + wm + lr) * K + lk8;
  const u16* Wp0 = W + (long)(bn0 + wn + lr) * K + lk8;
  for (int k0 = 0; k0 < K; k0 += 32) {
    short8 a0 = *reinterpret_cast<const short8*>(Ap0 + k0);
    short8 a1 = *reinterpret_cast<const short8*>(Ap0 + (long)16 * K + k0);
    short8 b0 = *reinterpret_cast<const short8*>(Wp0 + k0);
    short8 b1 = *reinterpret_cast<const short8*>(Wp0 + (long)16 * K + k0);
    acc[0][0] = __builtin_amdgcn_mfma_f32_16x16x32_bf16(a0, b0, acc[0][0], 0, 0, 0);
    acc[0][1] = __builtin_amdgcn_mfma_f32_16x16x32_bf16(a0, b1, acc[0][1], 0, 0, 0);
    acc[1][0] = __builtin_amdgcn_mfma_f32_16x16x32_bf16(a1, b0, acc[1][0], 0, 0, 0);
    acc[1][1] = __builtin_amdgcn_mfma_f32_16x16x32_bf16(a1, b1, acc[1][1], 0, 0, 0);
  }
  #pragma unroll
  for (int mt = 0; mt < 2; ++mt)
  #pragma unroll
  for (int nt = 0; nt < 2; ++nt) {
    int n = bn0 + wn + 16 * nt + lr;
    float bv = bias[n];
    #pragma unroll
    for (int r = 0; r < 4; ++r) {
      int m = bm0 + wm + 16 * mt + (l >> 4) * 4 + r;
      out[(long)m * N + n] = f2bf(acc[mt][nt][r] + bv);
    }
  }
}

// ---------------- LSTM scan v9.2: v9 + conflict-free hbuf (256B rows, 16B-chunk XOR) ----
// Read: lane l, row lr=l&15, chunk ch=4ks+lk -> phys ch^lr; bank 4*((ch^lr)&7): 2-way, free.
// Write: batch lk -> row 4lk, col j: phys chunk (j>>3)^(4lk). Same involution both sides.
__device__ __forceinline__ void lstm_scan9_body(
    const float* __restrict__ X, const u16* __restrict__ Whh,
    u16* __restrict__ Hout, int dir, int bat0)
{
  __shared__ __align__(16) u16 hbuf[2][16][128];   // 256B rows, swizzled (8KB)

  const int tid = threadIdx.x;
  const int l = tid & 63, w = tid >> 6;
  const int lr = l & 15, lk = l >> 4;

  short8 bfrag[4][4];
  #pragma unroll
  for (int g = 0; g < 4; ++g)
    #pragma unroll
    for (int ks = 0; ks < 4; ++ks)
      bfrag[g][ks] = *reinterpret_cast<const short8*>(
          Whh + (g * 128 + 16 * w + lr) * 128 + 32 * ks + 8 * lk);

  for (int i = tid; i < 2 * 16 * 128; i += 512) ((u16*)hbuf)[i] = 0;

  float c = 0.f;
  const f32x4 z4 = {0.f, 0.f, 0.f, 0.f};

  auto ldX = [&](int t) -> float4 {
    int ta = dir ? (S_ - 1 - t) : t;
    return *reinterpret_cast<const float4*>(
        X + (size_t)((ta * 16 + bat0 + lk) * 128 + 16 * w + lr) * 4);
  };
  float4 xA = ldX(0), xB = ldX(1), xC = ldX(2), xD;
  __syncthreads();

  auto step = [&](int t, float4& xc, float4& xt, int tload) {
    const int p = t & 1;
    short8 af[4];
    #pragma unroll
    for (int ks = 0; ks < 4; ++ks)
      af[ks] = *reinterpret_cast<const short8*>(&hbuf[p][lr][((4 * ks + lk) ^ lr) << 3]);
    f32x4 acc[4] = {z4, z4, z4, z4};
    #pragma unroll
    for (int g = 0; g < 4; ++g)
      #pragma unroll
      for (int ks = 0; ks < 4; ++ks)
        acc[g] = __builtin_amdgcn_mfma_f32_16x16x32_bf16(af[ks], bfrag[g][ks], acc[g], 0, 0, 0);
    if (tload < S_) xt = ldX(tload);
    float zi = acc[0][0] + xc.x;
    float zf = acc[1][0] + xc.y;
    float zg = acc[2][0] + xc.z;
    float zo = acc[3][0] + xc.w;
    float si = __fdividef(1.f, 1.f + __expf(-zi));
    float sf = __fdividef(1.f, 1.f + __expf(-zf));
    float so = __fdividef(1.f, 1.f + __expf(-zo));
    float eg = __expf(2.f * zg);
    float tg = 1.f - __fdividef(2.f, eg + 1.f);
    c = sf * c + si * tg;
    float ec = __expf(2.f * c);
    float tc = 1.f - __fdividef(2.f, ec + 1.f);
    u16 hb = f2bf(so * tc);
    int ta = dir ? (S_ - 1 - t) : t;
    int j = 16 * w + lr;
    hbuf[p ^ 1][4 * lk][(((j >> 3) ^ (4 * lk)) << 3) + (j & 7)] = hb;
    Hout[((size_t)(bat0 + lk) * S_ + ta) * 256 + dir * 128 + j] = hb;
    asm volatile("s_waitcnt lgkmcnt(0)" ::: "memory");
    __builtin_amdgcn_s_barrier();
  };

  for (int t = 0; t < S_; t += 4) {
    step(t,     xA, xD, t + 3);
    step(t + 1, xB, xA, t + 4);
    step(t + 2, xC, xB, t + 5);
    step(t + 3, xD, xC, t + 6);
  }
}

// ---------------- fused dispatch: blocks 0..7 = scan(dir,batgrp), blocks 8.. = BT-GEMM ----------------
__global__ __launch_bounds__(512, 1) void scan_fused(
    const float* __restrict__ Xf, const float* __restrict__ Xb,
    const u16* __restrict__ Whhf, const u16* __restrict__ Whhb,
    u16* __restrict__ Hout,
    const u16* __restrict__ gA, const u16* __restrict__ gW,
    const float* __restrict__ gb, u16* __restrict__ gOut, int gK)
{
  if (blockIdx.x < 8) {
    int dir = blockIdx.x & 1, bat0 = (blockIdx.x >> 1) * 4;
    lstm_scan9_body(dir ? Xb : Xf, dir ? Whhb : Whhf, Hout, dir, bat0);
  } else {
    int bi = blockIdx.x - 8;
    gemm_bt_body8(gA, gW, gb, gOut, 256, gK, bi & 1, bi >> 1);
  }
}

// ---------------- transpose body + kernels ----------------
__device__ __forceinline__ void transpose_body(const u16* __restrict__ in, u16* __restrict__ out,
                                               int bz, int s0, int d0)
{
  __shared__ u16 tile[32][33];
  int tx = threadIdx.x & 31, ty = threadIdx.x >> 5;
  const u16* ip = in + (long)bz * 512 * 256;
  u16* op = out + (long)bz * 256 * 512;
  #pragma unroll
  for (int k = 0; k < 32; k += 8) tile[ty + k][tx] = ip[(long)(s0 + ty + k) * 256 + d0 + tx];
  __syncthreads();
  #pragma unroll
  for (int k = 0; k < 32; k += 8) op[(long)(d0 + ty + k) * 512 + s0 + tx] = tile[tx][ty + k];
}

__global__ __launch_bounds__(256) void transpose_g(const u16* __restrict__ in, u16* __restrict__ out)
{
  transpose_body(in, out, blockIdx.z, blockIdx.x * 32, blockIdx.y * 32);
}

// wattn GEMM (512 blocks) || transpose (2048 blocks), both read gcur
__global__ __launch_bounds__(256) void wattn_trans(
    const u16* __restrict__ gcur, const u16* __restrict__ wW, const float* __restrict__ wb,
    u16* __restrict__ qb, u16* __restrict__ gT)
{
  if (blockIdx.x < 512) {
    int b = blockIdx.x;
    gemm_bt_body<0, true, 0, false>(gcur, wW, wb, nullptr, nullptr, nullptr, qb,
                                    8192, 256, 256, 0, 0, 0, b & 3, b >> 2, 0, threadIdx.x);
  } else {
    int b = blockIdx.x - 512;
    int bz = b >> 7, rem = b & 127;
    transpose_body(gcur, gT, bz, (rem & 15) * 32, (rem >> 4) * 32);
  }
}

// ---------------- coalesced mean over S of concat[lstm_out, g_final] ----------------
__global__ __launch_bounds__(256) void mean_cat(
    const u16* __restrict__ lstm, const u16* __restrict__ gf, float* __restrict__ dout)
{
  int b = blockIdx.x, tid = threadIdx.x;
  float sl = 0.f, sg = 0.f;
  for (int t = 0; t < 512; ++t) {
    sl += bf2f(lstm[((size_t)b * 512 + t) * 256 + tid]);
    sg += bf2f(gf[((size_t)b * 512 + t) * 256 + tid]);
  }
  dout[32 + b * 512 + tid]       = sl * (1.f / 512.f);
  dout[32 + b * 512 + 256 + tid] = sg * (1.f / 512.f);
}

// ---------------- head: fcA -> leaky -> fcB -> leaky -> fcC ----------------
__global__ __launch_bounds__(256) void head_kernel(
    const float* __restrict__ hidden,
    const float* __restrict__ fcA_W, const float* __restrict__ fcA_b,
    const float* __restrict__ fcB_W, const float* __restrict__ fcB_b,
    const float* __restrict__ fcC_W, const float* __restrict__ fcC_b,
    float* __restrict__ y)
{
  __shared__ float hb[16 * 512];
  __shared__ float ab[16 * 128];
  __shared__ float bb[16 * 32];
  int tid = threadIdx.x;
  for (int i = tid; i < 8192; i += 256) hb[i] = hidden[i];
  __syncthreads();
  for (int o = tid; o < 2048; o += 256) {
    int b = o >> 7, jj = o & 127;
    float acc = fcA_b[jj];
    const float* wrow = fcA_W + jj * 512;
    const float* hrow = hb + b * 512;
    for (int k = 0; k < 512; ++k) acc += hrow[k] * wrow[k];
    ab[o] = acc > 0.f ? acc : 0.1f * acc;
  }
  __syncthreads();
  for (int o = tid; o < 512; o += 256) {
    int b = o >> 5, jj = o & 31;
    float acc = fcB_b[jj];
    for (int k = 0; k < 128; ++k) acc += ab[b * 128 + k] * fcB_W[jj * 128 + k];
    bb[o] = acc > 0.f ? acc : 0.1f * acc;
  }
  __syncthreads();
  if (tid < 32) {
    int b = tid >> 1, jj = tid & 1;
    float acc = fcC_b[jj];
    for (int k = 0; k < 32; ++k) acc += bb[b * 32 + k] * fcC_W[jj * 32 + k];
    y[b * 2 + jj] = acc;
  }
}

extern "C" void kernel_launch(void* const* d_in, const int* in_sizes, int n_in,
                              void* d_out, int out_size, void* d_ws, size_t ws_size,
                              hipStream_t stream)
{
  const float* x       = (const float*)d_in[0];
  const float* adj     = (const float*)d_in[1];
  const float* l0f_Wih = (const float*)d_in[2];
  const float* l0f_Whh = (const float*)d_in[3];
  const float* l0f_bih = (const float*)d_in[4];
  const float* l0f_bhh = (const float*)d_in[5];
  const float* l0b_Wih = (const float*)d_in[6];
  const float* l0b_Whh = (const float*)d_in[7];
  const float* l0b_bih = (const float*)d_in[8];
  const float* l0b_bhh = (const float*)d_in[9];
  const float* l1f_Wih = (const float*)d_in[10];
  const float* l1f_Whh = (const float*)d_in[11];
  const float* l1f_bih = (const float*)d_in[12];
  const float* l1f_bhh = (const float*)d_in[13];
  const float* l1b_Wih = (const float*)d_in[14];
  const float* l1b_Whh = (const float*)d_in[15];
  const float* l1b_bih = (const float*)d_in[16];
  const float* l1b_bhh = (const float*)d_in[17];
  const float* fc1_W   = (const float*)d_in[18];
  const float* fc1_b   = (const float*)d_in[19];
  const float* wattn_W = (const float*)d_in[20];
  const float* wattn_b = (const float*)d_in[21];
  const float* lin0_W  = (const float*)d_in[22];
  const float* lin0_b  = (const float*)d_in[23];
  const float* lin1_W  = (const float*)d_in[24];
  const float* lin1_b  = (const float*)d_in[25];
  const float* linf_W  = (const float*)d_in[26];
  const float* linf_b  = (const float*)d_in[27];
  const float* fcA_W   = (const float*)d_in[28];
  const float* fcA_b   = (const float*)d_in[29];
  const float* fcB_W   = (const float*)d_in[30];
  const float* fcB_b   = (const float*)d_in[31];
  const float* fcC_W   = (const float*)d_in[32];
  const float* fcC_b   = (const float*)d_in[33];

  char* wp = (char*)d_ws;
  auto alloc = [&](size_t n) -> void* { void* p = wp; wp += (n + 255) & ~(size_t)255; return p; };

  u16* x_bf     = (u16*)alloc((size_t)B_ * S_ * D_ * 2);
  u16* w0f_ih   = (u16*)alloc((size_t)512 * 1024 * 2);
  u16* w0b_ih   = (u16*)alloc((size_t)512 * 1024 * 2);
  u16* w1f_ih   = (u16*)alloc((size_t)512 * 256 * 2);
  u16* w1b_ih   = (u16*)alloc((size_t)512 * 256 * 2);
  u16* w0f_hh   = (u16*)alloc((size_t)512 * 128 * 2);
  u16* w0b_hh   = (u16*)alloc((size_t)512 * 128 * 2);
  u16* w1f_hh   = (u16*)alloc((size_t)512 * 128 * 2);
  u16* w1b_hh   = (u16*)alloc((size_t)512 * 128 * 2);
  u16* wfc1     = (u16*)alloc((size_t)256 * 1024 * 2);
  u16* wattn_bf = (u16*)alloc((size_t)4 * 256 * 256 * 2);
  u16* wlin0_bf = (u16*)alloc((size_t)4 * 256 * 256 * 2);
  u16* wlin1_bf = (u16*)alloc((size_t)4 * 256 * 256 * 2);
  u16* wlinf_bf = (u16*)alloc((size_t)256 * 256 * 2);
  float* bias4  = (float*)alloc((size_t)2048 * 4);
  float* X0f    = (float*)alloc((size_t)S_ * 16 * 512 * 4);
  float* X0b    = (float*)alloc((size_t)S_ * 16 * 512 * 4);
  u16* h0       = (u16*)alloc((size_t)B_ * S_ * 256 * 2);
  u16* lstm_out = (u16*)alloc((size_t)B_ * S_ * 256 * 2);
  u16* gA       = (u16*)alloc((size_t)B_ * S_ * 256 * 2);
  u16* gB       = (u16*)alloc((size_t)B_ * S_ * 256 * 2);
  u16* qb       = (u16*)alloc((size_t)B_ * S_ * 256 * 2);
  u16* gT       = (u16*)alloc((size_t)B_ * S_ * 256 * 2);
  u16* t1       = (u16*)alloc((size_t)B_ * S_ * 256 * 2);
  u16* t2       = (u16*)alloc((size_t)B_ * S_ * 256 * 2);
  u16* abf      = (u16*)alloc((size_t)B_ * S_ * S_ * 2);
  float* rsum   = (float*)alloc((size_t)B_ * S_ * 4);

  // ---- conversions (14 segments) ----
  CvtSegs cs;
  int nb = 0, si = 0;
  auto seg = [&](const float* s, u16* d, int n) {
    cs.src[si] = (const float4*)s; cs.dst[si] = (short4*)d;
    cs.blk0[si] = nb; nb += (n / 4 + 255) / 256; ++si;
  };
  seg(x, x_bf, B_ * S_ * D_);
  seg(l0f_Wih, w0f_ih, 512 * 1024);
  seg(l0b_Wih, w0b_ih, 512 * 1024);
  seg(l1f_Wih, w1f_ih, 512 * 256);
  seg(l1b_Wih, w1b_ih, 512 * 256);
  seg(l0f_Whh, w0f_hh, 512 * 128);
  seg(l0b_Whh, w0b_hh, 512 * 128);
  seg(l1f_Whh, w1f_hh, 512 * 128);
  seg(l1b_Whh, w1b_hh, 512 * 128);
  seg(fc1_W, wfc1, 256 * 1024);
  seg(wattn_W, wattn_bf, 4 * 256 * 256);
  seg(lin0_W, wlin0_bf, 4 * 256 * 256);
  seg(lin1_W, wlin1_bf, 4 * 256 * 256);
  seg(linf_W, wlinf_bf, 256 * 256);
  for (int k = si; k <= 14; ++k) cs.blk0[k] = nb;
  cvt_multi<<<nb, 256, 0, stream>>>(cs);
  bias_prep<<<8, 256, 0, stream>>>(l0f_bih, l0f_bhh, l0b_bih, l0b_bhh,
                                   l1f_bih, l1f_bhh, l1b_bih, l1b_bhh, bias4);

  // ---- LSTM layer 0: fused f/b projections, then scan (+fc1 GEMM fused) ----
  proj2<<<dim3(8, 128, 2), 256, 0, stream>>>(x_bf, w0f_ih, w0b_ih, bias4, X0f, X0b, 1024);
  scan_fused<<<8 + 256, 512, 0, stream>>>(X0f, X0b, w0f_hh, w0b_hh, h0,
                                          x_bf, wfc1, fc1_b, gA, 1024);
  // ---- LSTM layer 1 (+ GAT layer-0 wattn GEMM fused) ----
  proj2<<<dim3(8, 128, 2), 256, 0, stream>>>(h0, w1f_ih, w1b_ih, bias4 + 1024, X0f, X0b, 256);
  scan_fused<<<8 + 256, 512, 0, stream>>>(X0f, X0b, w1f_hh, w1b_hh, lstm_out,
                                          gA, wattn_bf, wattn_b, qb, 256);

  // ---- GAT (serial dispatches; rowsum fused into score epilogue via atomics) ----
  u16* gcur = gA; u16* gnext = gB;
  for (int lyr = 0; lyr < 4; ++lyr) {
    if (lyr == 0)
      transpose_g<<<dim3(16, 8, 16), 256, 0, stream>>>(gcur, gT);
    else
      wattn_trans<<<512 + 2048, 256, 0, stream>>>(gcur, wattn_bf + lyr * 65536,
                                                  wattn_b + lyr * 256, qb, gT);
    hipMemsetAsync(rsum, 0, (size_t)B_ * S_ * 4, stream);
    gemm_bt<2, true, 0, false><<<dim3(8, 8, 16), 256, 0, stream>>>(
        qb, gcur, nullptr, nullptr, adj, rsum, abf, 512, 512, 256, 131072, 131072, 262144);
    gemm_bt<3, true, 0, false><<<dim3(4, 8, 16), 256, 0, stream>>>(
        abf, gT, nullptr, nullptr, rsum, nullptr, t1, 512, 256, 512, 262144, 131072, 131072);
    gemm_bt<1, true, 0, false><<<dim3(4, 128, 1), 256, 0, stream>>>(
        t1, wlin0_bf + lyr * 65536, lin0_b + lyr * 256, nullptr, nullptr, nullptr, t2,
        8192, 256, 256, 0, 0, 0);
    gemm_bt<1, true, 0, true><<<dim3(4, 128, 1), 256, 0, stream>>>(
        t2, wlin1_bf + lyr * 65536, lin1_b + lyr * 256, gcur, nullptr, nullptr, gnext,
        8192, 256, 256, 0, 0, 0);
    u16* tmp = gcur; gcur = gnext; gnext = tmp;
  }
  gemm_bt<0, true, 0, false><<<dim3(4, 128, 1), 256, 0, stream>>>(
      gcur, wlinf_bf, linf_b, nullptr, nullptr, nullptr, t2, 8192, 256, 256, 0, 0, 0);

  // ---- pool + head ----
  mean_cat<<<16, 256, 0, stream>>>(lstm_out, t2, (float*)d_out);
  head_kernel<<<1, 256, 0, stream>>>((const float*)d_out + 32,
                                     fcA_W, fcA_b, fcB_W, fcB_b, fcC_W, fcC_b,
                                     (float*)d_out);
}

// Round 18
// 1206.006 us; speedup vs baseline: 5.2476x; 1.0056x over previous
//
#include <hip/hip_runtime.h>
#include <stdint.h>

#define B_ 16
#define S_ 512
#define D_ 1024
#define H4 512
#define G_ 256

typedef unsigned short u16;
using short8 = __attribute__((ext_vector_type(8))) short;
using f32x4  = __attribute__((ext_vector_type(4))) float;

__device__ __forceinline__ u16 f2bf(float f){
  unsigned int u = __float_as_uint(f);
  u += 0x7fffu + ((u >> 16) & 1u);
  return (u16)(u >> 16);
}
__device__ __forceinline__ float bf2f(u16 h){
  return __uint_as_float(((unsigned int)h) << 16);
}

// ---------------- single-dispatch f32 -> bf16 convert over all segments ----------------
struct CvtSegs {
  const float4* src[14];
  short4* dst[14];
  int blk0[15];
};
__global__ __launch_bounds__(256) void cvt_multi(CvtSegs cs){
  int blk = blockIdx.x;
  int s = 0;
  #pragma unroll
  for (int k = 0; k < 14; ++k) if (cs.blk0[k + 1] <= blk) s = k + 1;
  int i = (blk - cs.blk0[s]) * 256 + threadIdx.x;
  float4 v = cs.src[s][i];
  short4 o;
  o.x = (short)f2bf(v.x); o.y = (short)f2bf(v.y);
  o.z = (short)f2bf(v.z); o.w = (short)f2bf(v.w);
  cs.dst[s][i] = o;
}

// ---------------- LSTM bias sums (bih+bhh) ----------------
__global__ __launch_bounds__(256) void bias_prep(const float* a,const float* b,const float* c,const float* d,
                                                 const float* e,const float* f,const float* g,const float* h,
                                                 float* out){
  int i = blockIdx.x * 256 + threadIdx.x;
  if (i >= 2048) return;
  int p = i >> 9, k = i & 511;
  const float* x1 = (p==0)?a:(p==1)?c:(p==2)?e:g;
  const float* x2 = (p==0)?b:(p==1)?d:(p==2)?f:h;
  out[i] = x1[k] + x2[k];
}

// ---------------- MFMA BT-GEMM body (256-lane slice, 64x64 tile) ----------------
// EPI: 0=none, 1=relu, 2=score-mask (sigmoid+adj+eye; ex=adj, aux=rsum atomic out),
//      3=row-divide (ex=rsum). PERM: 0 = row-major out, 2 = gate-interleaved X layout
template<int EPI, bool OUT_BF16, int PERM, bool RESID>
__device__ __forceinline__ void gemm_bt_body(
    const u16* __restrict__ A, const u16* __restrict__ W,
    const float* __restrict__ bias, const u16* __restrict__ resid,
    const float* __restrict__ ex, float* __restrict__ aux,
    void* __restrict__ outp, int M, int N, int K,
    long sA, long sW, long sO, int bx, int by, int bz, int tid)
{
  const u16* Ab = A + (long)bz * sA;
  const u16* Wb = W + (long)bz * sW;
  const int bm0 = by * 64, bn0 = bx * 64;
  const int l = tid & 63, wid = tid >> 6;
  const int wm = (wid >> 1) * 32, wn = (wid & 1) * 32;
  const int lr = l & 15, lk8 = (l >> 4) * 8;

  const f32x4 z4 = {0.f, 0.f, 0.f, 0.f};
  f32x4 acc[2][2] = {{z4, z4}, {z4, z4}};

  const u16* Ap0 = Ab + (long)(bm0 + wm + lr) * K + lk8;
  const u16* Wp0 = Wb + (long)(bn0 + wn + lr) * K + lk8;
  for (int k0 = 0; k0 < K; k0 += 32) {
    short8 a0 = *reinterpret_cast<const short8*>(Ap0 + k0);
    short8 a1 = *reinterpret_cast<const short8*>(Ap0 + (long)16 * K + k0);
    short8 b0 = *reinterpret_cast<const short8*>(Wp0 + k0);
    short8 b1 = *reinterpret_cast<const short8*>(Wp0 + (long)16 * K + k0);
    acc[0][0] = __builtin_amdgcn_mfma_f32_16x16x32_bf16(a0, b0, acc[0][0], 0, 0, 0);
    acc[0][1] = __builtin_amdgcn_mfma_f32_16x16x32_bf16(a0, b1, acc[0][1], 0, 0, 0);
    acc[1][0] = __builtin_amdgcn_mfma_f32_16x16x32_bf16(a1, b0, acc[1][0], 0, 0, 0);
    acc[1][1] = __builtin_amdgcn_mfma_f32_16x16x32_bf16(a1, b1, acc[1][1], 0, 0, 0);
  }
  float rp[2][4] = {{0.f,0.f,0.f,0.f},{0.f,0.f,0.f,0.f}};
  #pragma unroll
  for (int mt = 0; mt < 2; ++mt)
  #pragma unroll
  for (int nt = 0; nt < 2; ++nt) {
    int n = bn0 + wn + 16 * nt + lr;
    float bv = bias ? bias[n] : 0.f;
    #pragma unroll
    for (int r = 0; r < 4; ++r) {
      int m = bm0 + wm + 16 * mt + (l >> 4) * 4 + r;
      float v = acc[mt][nt][r] + bv;
      if (EPI == 1) v = fmaxf(v, 0.f);
      if (EPI == 2) {
        float sg = __fdividef(1.f, 1.f + __expf(-v));
        v = (n == m) ? (sg + 1e-5f) : sg * ex[((long)bz * 512 + m) * 512 + n];
        rp[mt][r] += v;
      }
      if (EPI == 3) v = __fdividef(v, ex[(long)bz * 512 + m]);
      if (RESID) v += bf2f(resid[(long)m * N + n]);
      long oi;
      if (PERM == 2) {
        int t = m & 511, b = m >> 9;
        oi = (long)((t * 16 + b) * 128 + (n & 127)) * 4 + (n >> 7);
      } else {
        oi = (long)bz * sO + (long)m * N + n;
      }
      if (OUT_BF16) ((u16*)outp)[oi] = f2bf(v);
      else          ((float*)outp)[oi] = v;
    }
  }
  if (EPI == 2) {
    #pragma unroll
    for (int mt = 0; mt < 2; ++mt)
    #pragma unroll
    for (int r = 0; r < 4; ++r) {
      float s = rp[mt][r];
      #pragma unroll
      for (int off = 1; off < 16; off <<= 1) s += __shfl_xor(s, off);
      if (lr == 0) {
        int m = bm0 + wm + 16 * mt + (l >> 4) * 4 + r;
        atomicAdd(&aux[(long)bz * 512 + m], s);
      }
    }
  }
}

template<int EPI, bool OUT_BF16, int PERM, bool RESID>
__global__ __launch_bounds__(256) void gemm_bt(
    const u16* __restrict__ A, const u16* __restrict__ W,
    const float* __restrict__ bias, const u16* __restrict__ resid,
    const float* __restrict__ ex, float* __restrict__ aux,
    void* __restrict__ outp, int M, int N, int K,
    long sA, long sW, long sO)
{
  gemm_bt_body<EPI, OUT_BF16, PERM, RESID>(A, W, bias, resid, ex, aux, outp, M, N, K,
                                           sA, sW, sO, blockIdx.x, blockIdx.y, blockIdx.z,
                                           threadIdx.x);
}

// ---------------- fused f/b input projections (PERM2, f32 out) ----------------
__global__ __launch_bounds__(256) void proj2(
    const u16* __restrict__ A, const u16* __restrict__ W0, const u16* __restrict__ W1,
    const float* __restrict__ bias, float* __restrict__ O0, float* __restrict__ O1, int K)
{
  int z = blockIdx.z;
  gemm_bt_body<0, false, 2, false>(A, z ? W1 : W0, bias + z * 512, nullptr, nullptr, nullptr,
                                   z ? O1 : O0, 8192, 512, K, 0, 0, 0,
                                   blockIdx.x, blockIdx.y, 0, threadIdx.x);
}

// ---------------- 8-wave BT-GEMM body (512 thr, 64x128 tile, bf16 out, bias, EPI) ----------
template<int EPI, bool RESID>
__device__ __forceinline__ void gemm_bt_body8(
    const u16* __restrict__ A, const u16* __restrict__ W,
    const float* __restrict__ bias, const u16* __restrict__ resid,
    u16* __restrict__ out, int N, int K, int bx, int by)
{
  const int bm0 = by * 64, bn0 = bx * 128;
  const int tid = threadIdx.x;
  const int l = tid & 63, wid = tid >> 6;
  const int wm = (wid >> 2) * 32, wn = (wid & 3) * 32;
  const int lr = l & 15, lk8 = (l >> 4) * 8;

  const f32x4 z4 = {0.f, 0.f, 0.f, 0.f};
  f32x4 acc[2][2] = {{z4, z4}, {z4, z4}};

  const u16* Ap0 = A + (long)(bm0 + wm + lr) * K + lk8;
  const u16* Wp0 = W + (long)(bn0 + wn + lr) * K + lk8;
  for (int k0 = 0; k0 < K; k0 += 32) {
    short8 a0 = *reinterpret_cast<const short8*>(Ap0 + k0);
    short8 a1 = *reinterpret_cast<const short8*>(Ap0 + (long)16 * K + k0);
    short8 b0 = *reinterpret_cast<const short8*>(Wp0 + k0);
    short8 b1 = *reinterpret_cast<const short8*>(Wp0 + (long)16 * K + k0);
    acc[0][0] = __builtin_amdgcn_mfma_f32_16x16x32_bf16(a0, b0, acc[0][0], 0, 0, 0);
    acc[0][1] = __builtin_amdgcn_mfma_f32_16x16x32_bf16(a0, b1, acc[0][1], 0, 0, 0);
    acc[1][0] = __builtin_amdgcn_mfma_f32_16x16x32_bf16(a1, b0, acc[1][0], 0, 0, 0);
    acc[1][1] = __builtin_amdgcn_mfma_f32_16x16x32_bf16(a1, b1, acc[1][1], 0, 0, 0);
  }
  #pragma unroll
  for (int mt = 0; mt < 2; ++mt)
  #pragma unroll
  for (int nt = 0; nt < 2; ++nt) {
    int n = bn0 + wn + 16 * nt + lr;
    float bv = bias[n];
    #pragma unroll
    for (int r = 0; r < 4; ++r) {
      int m = bm0 + wm + 16 * mt + (l >> 4) * 4 + r;
      float v = acc[mt][nt][r] + bv;
      if (EPI == 1) v = fmaxf(v, 0.f);
      if (RESID) v += bf2f(resid[(long)m * N + n]);
      out[(long)m * N + n] = f2bf(v);
    }
  }
}

template<int EPI, bool RESID>
__global__ __launch_bounds__(512) void gemm8(
    const u16* __restrict__ A, const u16* __restrict__ W,
    const float* __restrict__ bias, const u16* __restrict__ resid,
    u16* __restrict__ out, int N, int K)
{
  gemm_bt_body8<EPI, RESID>(A, W, bias, resid, out, N, K, blockIdx.x, blockIdx.y);
}

// ---------------- LSTM scan v9.2: conflict-free hbuf (256B rows, 16B-chunk XOR) ----------
__device__ __forceinline__ void lstm_scan9_body(
    const float* __restrict__ X, const u16* __restrict__ Whh,
    u16* __restrict__ Hout, int dir, int bat0)
{
  __shared__ __align__(16) u16 hbuf[2][16][128];   // 256B rows, swizzled (8KB)

  const int tid = threadIdx.x;
  const int l = tid & 63, w = tid >> 6;
  const int lr = l & 15, lk = l >> 4;

  short8 bfrag[4][4];
  #pragma unroll
  for (int g = 0; g < 4; ++g)
    #pragma unroll
    for (int ks = 0; ks < 4; ++ks)
      bfrag[g][ks] = *reinterpret_cast<const short8*>(
          Whh + (g * 128 + 16 * w + lr) * 128 + 32 * ks + 8 * lk);

  for (int i = tid; i < 2 * 16 * 128; i += 512) ((u16*)hbuf)[i] = 0;

  float c = 0.f;
  const f32x4 z4 = {0.f, 0.f, 0.f, 0.f};

  auto ldX = [&](int t) -> float4 {
    int ta = dir ? (S_ - 1 - t) : t;
    return *reinterpret_cast<const float4*>(
        X + (size_t)((ta * 16 + bat0 + lk) * 128 + 16 * w + lr) * 4);
  };
  float4 xA = ldX(0), xB = ldX(1), xC = ldX(2), xD;
  __syncthreads();

  auto step = [&](int t, float4& xc, float4& xt, int tload) {
    const int p = t & 1;
    short8 af[4];
    #pragma unroll
    for (int ks = 0; ks < 4; ++ks)
      af[ks] = *reinterpret_cast<const short8*>(&hbuf[p][lr][((4 * ks + lk) ^ lr) << 3]);
    f32x4 acc[4] = {z4, z4, z4, z4};
    #pragma unroll
    for (int g = 0; g < 4; ++g)
      #pragma unroll
      for (int ks = 0; ks < 4; ++ks)
        acc[g] = __builtin_amdgcn_mfma_f32_16x16x32_bf16(af[ks], bfrag[g][ks], acc[g], 0, 0, 0);
    if (tload < S_) xt = ldX(tload);
    float zi = acc[0][0] + xc.x;
    float zf = acc[1][0] + xc.y;
    float zg = acc[2][0] + xc.z;
    float zo = acc[3][0] + xc.w;
    float si = __fdividef(1.f, 1.f + __expf(-zi));
    float sf = __fdividef(1.f, 1.f + __expf(-zf));
    float so = __fdividef(1.f, 1.f + __expf(-zo));
    float eg = __expf(2.f * zg);
    float tg = 1.f - __fdividef(2.f, eg + 1.f);
    c = sf * c + si * tg;
    float ec = __expf(2.f * c);
    float tc = 1.f - __fdividef(2.f, ec + 1.f);
    u16 hb = f2bf(so * tc);
    int ta = dir ? (S_ - 1 - t) : t;
    int j = 16 * w + lr;
    hbuf[p ^ 1][4 * lk][(((j >> 3) ^ (4 * lk)) << 3) + (j & 7)] = hb;
    Hout[((size_t)(bat0 + lk) * S_ + ta) * 256 + dir * 128 + j] = hb;
    asm volatile("s_waitcnt lgkmcnt(0)" ::: "memory");
    __builtin_amdgcn_s_barrier();
  };

  for (int t = 0; t < S_; t += 4) {
    step(t,     xA, xD, t + 3);
    step(t + 1, xB, xA, t + 4);
    step(t + 2, xC, xB, t + 5);
    step(t + 3, xD, xC, t + 6);
  }
}

// ---------------- fused dispatch: blocks 0..7 = scan(dir,batgrp), blocks 8.. = BT-GEMM ----------------
__global__ __launch_bounds__(512, 1) void scan_fused(
    const float* __restrict__ Xf, const float* __restrict__ Xb,
    const u16* __restrict__ Whhf, const u16* __restrict__ Whhb,
    u16* __restrict__ Hout,
    const u16* __restrict__ gA, const u16* __restrict__ gW,
    const float* __restrict__ gb, u16* __restrict__ gOut, int gK)
{
  if (blockIdx.x < 8) {
    int dir = blockIdx.x & 1, bat0 = (blockIdx.x >> 1) * 4;
    lstm_scan9_body(dir ? Xb : Xf, dir ? Whhb : Whhf, Hout, dir, bat0);
  } else {
    int bi = blockIdx.x - 8;
    gemm_bt_body8<0, false>(gA, gW, gb, nullptr, gOut, 256, gK, bi & 1, bi >> 1);
  }
}

// ---------------- transpose body + kernels ----------------
__device__ __forceinline__ void transpose_body(const u16* __restrict__ in, u16* __restrict__ out,
                                               int bz, int s0, int d0)
{
  __shared__ u16 tile[32][33];
  int tx = threadIdx.x & 31, ty = threadIdx.x >> 5;
  const u16* ip = in + (long)bz * 512 * 256;
  u16* op = out + (long)bz * 256 * 512;
  #pragma unroll
  for (int k = 0; k < 32; k += 8) tile[ty + k][tx] = ip[(long)(s0 + ty + k) * 256 + d0 + tx];
  __syncthreads();
  #pragma unroll
  for (int k = 0; k < 32; k += 8) op[(long)(d0 + ty + k) * 512 + s0 + tx] = tile[tx][ty + k];
}

__global__ __launch_bounds__(256) void transpose_g(const u16* __restrict__ in, u16* __restrict__ out)
{
  transpose_body(in, out, blockIdx.z, blockIdx.x * 32, blockIdx.y * 32);
}

// wattn GEMM (512 blocks) || transpose (2048 blocks), both read gcur
__global__ __launch_bounds__(256) void wattn_trans(
    const u16* __restrict__ gcur, const u16* __restrict__ wW, const float* __restrict__ wb,
    u16* __restrict__ qb, u16* __restrict__ gT)
{
  if (blockIdx.x < 512) {
    int b = blockIdx.x;
    gemm_bt_body<0, true, 0, false>(gcur, wW, wb, nullptr, nullptr, nullptr, qb,
                                    8192, 256, 256, 0, 0, 0, b & 3, b >> 2, 0, threadIdx.x);
  } else {
    int b = blockIdx.x - 512;
    int bz = b >> 7, rem = b & 127;
    transpose_body(gcur, gT, bz, (rem & 15) * 32, (rem >> 4) * 32);
  }
}

// ---------------- coalesced mean over S of concat[lstm_out, g_final] ----------------
__global__ __launch_bounds__(256) void mean_cat(
    const u16* __restrict__ lstm, const u16* __restrict__ gf, float* __restrict__ dout)
{
  int b = blockIdx.x, tid = threadIdx.x;
  float sl = 0.f, sg = 0.f;
  for (int t = 0; t < 512; ++t) {
    sl += bf2f(lstm[((size_t)b * 512 + t) * 256 + tid]);
    sg += bf2f(gf[((size_t)b * 512 + t) * 256 + tid]);
  }
  dout[32 + b * 512 + tid]       = sl * (1.f / 512.f);
  dout[32 + b * 512 + 256 + tid] = sg * (1.f / 512.f);
}

// ---------------- head: fcA -> leaky -> fcB -> leaky -> fcC ----------------
__global__ __launch_bounds__(256) void head_kernel(
    const float* __restrict__ hidden,
    const float* __restrict__ fcA_W, const float* __restrict__ fcA_b,
    const float* __restrict__ fcB_W, const float* __restrict__ fcB_b,
    const float* __restrict__ fcC_W, const float* __restrict__ fcC_b,
    float* __restrict__ y)
{
  __shared__ float hb[16 * 512];
  __shared__ float ab[16 * 128];
  __shared__ float bb[16 * 32];
  int tid = threadIdx.x;
  for (int i = tid; i < 8192; i += 256) hb[i] = hidden[i];
  __syncthreads();
  for (int o = tid; o < 2048; o += 256) {
    int b = o >> 7, jj = o & 127;
    float acc = fcA_b[jj];
    const float* wrow = fcA_W + jj * 512;
    const float* hrow = hb + b * 512;
    for (int k = 0; k < 512; ++k) acc += hrow[k] * wrow[k];
    ab[o] = acc > 0.f ? acc : 0.1f * acc;
  }
  __syncthreads();
  for (int o = tid; o < 512; o += 256) {
    int b = o >> 5, jj = o & 31;
    float acc = fcB_b[jj];
    for (int k = 0; k < 128; ++k) acc += ab[b * 128 + k] * fcB_W[jj * 128 + k];
    bb[o] = acc > 0.f ? acc : 0.1f * acc;
  }
  __syncthreads();
  if (tid < 32) {
    int b = tid >> 1, jj = tid & 1;
    float acc = fcC_b[jj];
    for (int k = 0; k < 32; ++k) acc += bb[b * 32 + k] * fcC_W[jj * 32 + k];
    y[b * 2 + jj] = acc;
  }
}

extern "C" void kernel_launch(void* const* d_in, const int* in_sizes, int n_in,
                              void* d_out, int out_size, void* d_ws, size_t ws_size,
                              hipStream_t stream)
{
  const float* x       = (const float*)d_in[0];
  const float* adj     = (const float*)d_in[1];
  const float* l0f_Wih = (const float*)d_in[2];
  const float* l0f_Whh = (const float*)d_in[3];
  const float* l0f_bih = (const float*)d_in[4];
  const float* l0f_bhh = (const float*)d_in[5];
  const float* l0b_Wih = (const float*)d_in[6];
  const float* l0b_Whh = (const float*)d_in[7];
  const float* l0b_bih = (const float*)d_in[8];
  const float* l0b_bhh = (const float*)d_in[9];
  const float* l1f_Wih = (const float*)d_in[10];
  const float* l1f_Whh = (const float*)d_in[11];
  const float* l1f_bih = (const float*)d_in[12];
  const float* l1f_bhh = (const float*)d_in[13];
  const float* l1b_Wih = (const float*)d_in[14];
  const float* l1b_Whh = (const float*)d_in[15];
  const float* l1b_bih = (const float*)d_in[16];
  const float* l1b_bhh = (const float*)d_in[17];
  const float* fc1_W   = (const float*)d_in[18];
  const float* fc1_b   = (const float*)d_in[19];
  const float* wattn_W = (const float*)d_in[20];
  const float* wattn_b = (const float*)d_in[21];
  const float* lin0_W  = (const float*)d_in[22];
  const float* lin0_b  = (const float*)d_in[23];
  const float* lin1_W  = (const float*)d_in[24];
  const float* lin1_b  = (const float*)d_in[25];
  const float* linf_W  = (const float*)d_in[26];
  const float* linf_b  = (const float*)d_in[27];
  const float* fcA_W   = (const float*)d_in[28];
  const float* fcA_b   = (const float*)d_in[29];
  const float* fcB_W   = (const float*)d_in[30];
  const float* fcB_b   = (const float*)d_in[31];
  const float* fcC_W   = (const float*)d_in[32];
  const float* fcC_b   = (const float*)d_in[33];

  char* wp = (char*)d_ws;
  auto alloc = [&](size_t n) -> void* { void* p = wp; wp += (n + 255) & ~(size_t)255; return p; };

  u16* x_bf     = (u16*)alloc((size_t)B_ * S_ * D_ * 2);
  u16* w0f_ih   = (u16*)alloc((size_t)512 * 1024 * 2);
  u16* w0b_ih   = (u16*)alloc((size_t)512 * 1024 * 2);
  u16* w1f_ih   = (u16*)alloc((size_t)512 * 256 * 2);
  u16* w1b_ih   = (u16*)alloc((size_t)512 * 256 * 2);
  u16* w0f_hh   = (u16*)alloc((size_t)512 * 128 * 2);
  u16* w0b_hh   = (u16*)alloc((size_t)512 * 128 * 2);
  u16* w1f_hh   = (u16*)alloc((size_t)512 * 128 * 2);
  u16* w1b_hh   = (u16*)alloc((size_t)512 * 128 * 2);
  u16* wfc1     = (u16*)alloc((size_t)256 * 1024 * 2);
  u16* wattn_bf = (u16*)alloc((size_t)4 * 256 * 256 * 2);
  u16* wlin0_bf = (u16*)alloc((size_t)4 * 256 * 256 * 2);
  u16* wlin1_bf = (u16*)alloc((size_t)4 * 256 * 256 * 2);
  u16* wlinf_bf = (u16*)alloc((size_t)256 * 256 * 2);
  float* bias4  = (float*)alloc((size_t)2048 * 4);
  float* X0f    = (float*)alloc((size_t)S_ * 16 * 512 * 4);
  float* X0b    = (float*)alloc((size_t)S_ * 16 * 512 * 4);
  u16* h0       = (u16*)alloc((size_t)B_ * S_ * 256 * 2);
  u16* lstm_out = (u16*)alloc((size_t)B_ * S_ * 256 * 2);
  u16* gA       = (u16*)alloc((size_t)B_ * S_ * 256 * 2);
  u16* gB       = (u16*)alloc((size_t)B_ * S_ * 256 * 2);
  u16* qb       = (u16*)alloc((size_t)B_ * S_ * 256 * 2);
  u16* gT       = (u16*)alloc((size_t)B_ * S_ * 256 * 2);
  u16* t1       = (u16*)alloc((size_t)B_ * S_ * 256 * 2);
  u16* t2       = (u16*)alloc((size_t)B_ * S_ * 256 * 2);
  u16* abf      = (u16*)alloc((size_t)B_ * S_ * S_ * 2);
  float* rsum   = (float*)alloc((size_t)4 * B_ * S_ * 4);

  // ---- conversions (14 segments) ----
  CvtSegs cs;
  int nb = 0, si = 0;
  auto seg = [&](const float* s, u16* d, int n) {
    cs.src[si] = (const float4*)s; cs.dst[si] = (short4*)d;
    cs.blk0[si] = nb; nb += (n / 4 + 255) / 256; ++si;
  };
  seg(x, x_bf, B_ * S_ * D_);
  seg(l0f_Wih, w0f_ih, 512 * 1024);
  seg(l0b_Wih, w0b_ih, 512 * 1024);
  seg(l1f_Wih, w1f_ih, 512 * 256);
  seg(l1b_Wih, w1b_ih, 512 * 256);
  seg(l0f_Whh, w0f_hh, 512 * 128);
  seg(l0b_Whh, w0b_hh, 512 * 128);
  seg(l1f_Whh, w1f_hh, 512 * 128);
  seg(l1b_Whh, w1b_hh, 512 * 128);
  seg(fc1_W, wfc1, 256 * 1024);
  seg(wattn_W, wattn_bf, 4 * 256 * 256);
  seg(lin0_W, wlin0_bf, 4 * 256 * 256);
  seg(lin1_W, wlin1_bf, 4 * 256 * 256);
  seg(linf_W, wlinf_bf, 256 * 256);
  for (int k = si; k <= 14; ++k) cs.blk0[k] = nb;
  cvt_multi<<<nb, 256, 0, stream>>>(cs);
  bias_prep<<<8, 256, 0, stream>>>(l0f_bih, l0f_bhh, l0b_bih, l0b_bhh,
                                   l1f_bih, l1f_bhh, l1b_bih, l1b_bhh, bias4);
  hipMemsetAsync(rsum, 0, (size_t)4 * B_ * S_ * 4, stream);   // all 4 layers at once

  // ---- LSTM layer 0: fused f/b projections, then scan (+fc1 GEMM fused) ----
  proj2<<<dim3(8, 128, 2), 256, 0, stream>>>(x_bf, w0f_ih, w0b_ih, bias4, X0f, X0b, 1024);
  scan_fused<<<8 + 256, 512, 0, stream>>>(X0f, X0b, w0f_hh, w0b_hh, h0,
                                          x_bf, wfc1, fc1_b, gA, 1024);
  // ---- LSTM layer 1 (+ GAT layer-0 wattn GEMM fused) ----
  proj2<<<dim3(8, 128, 2), 256, 0, stream>>>(h0, w1f_ih, w1b_ih, bias4 + 1024, X0f, X0b, 256);
  scan_fused<<<8 + 256, 512, 0, stream>>>(X0f, X0b, w1f_hh, w1b_hh, lstm_out,
                                          gA, wattn_bf, wattn_b, qb, 256);

  // ---- GAT (serial dispatches; rowsum fused into score epilogue; 8-wave GEMMs) ----
  u16* gcur = gA; u16* gnext = gB;
  for (int lyr = 0; lyr < 4; ++lyr) {
    float* rs = rsum + lyr * 8192;
    if (lyr == 0)
      transpose_g<<<dim3(16, 8, 16), 256, 0, stream>>>(gcur, gT);
    else
      wattn_trans<<<512 + 2048, 256, 0, stream>>>(gcur, wattn_bf + lyr * 65536,
                                                  wattn_b + lyr * 256, qb, gT);
    gemm_bt<2, true, 0, false><<<dim3(8, 8, 16), 256, 0, stream>>>(
        qb, gcur, nullptr, nullptr, adj, rs, abf, 512, 512, 256, 131072, 131072, 262144);
    gemm_bt<3, true, 0, false><<<dim3(4, 8, 16), 256, 0, stream>>>(
        abf, gT, nullptr, nullptr, rs, nullptr, t1, 512, 256, 512, 262144, 131072, 131072);
    gemm8<1, false><<<dim3(2, 128), 512, 0, stream>>>(
        t1, wlin0_bf + lyr * 65536, lin0_b + lyr * 256, nullptr, t2, 256, 256);
    gemm8<1, true><<<dim3(2, 128), 512, 0, stream>>>(
        t2, wlin1_bf + lyr * 65536, lin1_b + lyr * 256, gcur, gnext, 256, 256);
    u16* tmp = gcur; gcur = gnext; gnext = tmp;
  }
  gemm8<0, false><<<dim3(2, 128), 512, 0, stream>>>(
      gcur, wlinf_bf, linf_b, nullptr, t2, 256, 256);

  // ---- pool + head ----
  mean_cat<<<16, 256, 0, stream>>>(lstm_out, t2, (float*)d_out);
  head_kernel<<<1, 256, 0, stream>>>((const float*)d_out + 32,
                                     fcA_W, fcA_b, fcB_W, fcB_b, fcC_W, fcC_b,
                                     (float*)d_out);
}